// Round 2
// baseline (2097.168 us; speedup 1.0000x reference)
//
#include <hip/hip_runtime.h>
#include <math.h>

#define GSZ 256

typedef unsigned short u16;

__device__ __forceinline__ float bf2f(u16 u){
  union { unsigned int i; float f; } x; x.i = ((unsigned int)u) << 16; return x.f;
}
__device__ __forceinline__ u16 f2bf(float f){
  union { float ff; unsigned int i; } x; x.ff = f;
  unsigned int r = x.i + 0x7fffu + ((x.i >> 16) & 1u);
  return (u16)(r >> 16);
}
__device__ __forceinline__ float sigm(float x){ return 1.0f/(1.0f+__expf(-x)); }
__device__ __forceinline__ float siluf(float x){ return x/(1.0f+__expf(-x)); }

__device__ __forceinline__ float2 blockReduce2(float s, float ss){
  __shared__ float red[8];
  #pragma unroll
  for (int off=32; off>0; off>>=1){
    s  += __shfl_down(s, off, 64);
    ss += __shfl_down(ss, off, 64);
  }
  int lane = threadIdx.x & 63, wid = threadIdx.x >> 6;
  if (lane==0){ red[wid]=s; red[4+wid]=ss; }
  __syncthreads();
  float2 r;
  r.x = red[0]+red[1]+red[2]+red[3];
  r.y = red[4]+red[5]+red[6]+red[7];
  return r;
}

// token-shift + layernorm core (gamma/beta folded into downstream weights) -> bf16
__global__ __launch_bounds__(256) void shift_ln_kernel(
    const float* __restrict__ x, u16* __restrict__ out, int N)
{
  int n = blockIdx.x;
  int t = threadIdx.x;
  float v0 = (n > 0) ? x[(long long)(n-1)*512 + t] : 0.0f;   // shifted half
  float v1 = x[(long long)n*512 + 256 + t];                   // pass half
  float2 r = blockReduce2(v0+v1, fmaf(v0,v0,v1*v1));
  float mu = r.x * (1.0f/512.0f);
  float var = r.y * (1.0f/512.0f) - mu*mu;
  float rs = rsqrtf(var + 1e-5f);
  long long base = (long long)n*512;
  out[base + t]       = f2bf((v0-mu)*rs);
  out[base + 256 + t] = f2bf((v1-mu)*rs);
}

// W'[k,n] = g[k]*W[k,n]  (fp32 -> bf16)
__global__ void fuse_w_kernel(const float* __restrict__ g, const float* __restrict__ w,
                              u16* __restrict__ wout, int Nn, long long total)
{
  long long i = (long long)blockIdx.x*256 + threadIdx.x;
  if (i < total) {
    int k = (int)(i / Nn);
    wout[i] = f2bf(g[k] * w[i]);
  }
}

// b'[n] = bias[n] + sum_k b_ln[k]*W[k,n]   (fp32, reads ORIGINAL fp32 W)
__global__ void fuse_b_kernel(const float* __restrict__ bln, const float* __restrict__ w,
                              const float* __restrict__ bias, float* __restrict__ bout,
                              int K, int Nn)
{
  int nid = blockIdx.x*256 + threadIdx.x;
  if (nid < Nn) {
    float acc = bias[nid];
    for (int k = 0; k < K; ++k) acc = fmaf(bln[k], w[(long long)k*Nn + nid], acc);
    bout[nid] = acc;
  }
}

// C = silu(A @ W + bias); A: M x K bf16 (lda), W: K x ldw bf16 row-major, column window at wc0
// C: M x (gridDim.x*64) bf16 (ldc). grid = (cols/64, M/64)
__global__ __launch_bounds__(256) void gemm_bf16(
    const u16* __restrict__ A, int lda,
    const u16* __restrict__ W, int ldw, int wc0,
    u16* __restrict__ C, int ldc,
    const float* __restrict__ bias, int K)
{
  int bm = blockIdx.y * 64;
  int bn = blockIdx.x * 64;
  __shared__ float As[16][65];
  __shared__ float Ws[16][64];
  int t = threadIdx.x;
  int tx = t & 15, ty = t >> 4;
  float acc[4][4] = {};
  for (int k0 = 0; k0 < K; k0 += 16) {
    #pragma unroll
    for (int i = 0; i < 4; ++i) {
      int idx = t + i*256;
      int r = idx >> 4, c = idx & 15;
      As[c][r] = bf2f(A[(long long)(bm + r)*lda + k0 + c]);
    }
    #pragma unroll
    for (int i = 0; i < 4; ++i) {
      int idx = t + i*256;
      int r = idx >> 6, c = idx & 63;
      Ws[r][c] = bf2f(W[(long long)(k0 + r)*ldw + wc0 + bn + c]);
    }
    __syncthreads();
    #pragma unroll
    for (int kk = 0; kk < 16; ++kk) {
      float a[4], b[4];
      #pragma unroll
      for (int i = 0; i < 4; ++i) a[i] = As[kk][ty*4+i];
      #pragma unroll
      for (int j = 0; j < 4; ++j) b[j] = Ws[kk][tx*4+j];
      #pragma unroll
      for (int i = 0; i < 4; ++i)
        #pragma unroll
        for (int j = 0; j < 4; ++j)
          acc[i][j] = fmaf(a[i], b[j], acc[i][j]);
    }
    __syncthreads();
  }
  #pragma unroll
  for (int i = 0; i < 4; ++i) {
    int row = bm + ty*4 + i;
    ushort4 st;
    st.x = f2bf(siluf(acc[i][0] + bias[wc0+bn+tx*4+0]));
    st.y = f2bf(siluf(acc[i][1] + bias[wc0+bn+tx*4+1]));
    st.z = f2bf(siluf(acc[i][2] + bias[wc0+bn+tx*4+2]));
    st.w = f2bf(siluf(acc[i][3] + bias[wc0+bn+tx*4+3]));
    *(ushort4*)(C + (long long)row*ldc + bn + tx*4) = st;
  }
}

// y[n,c] = x[n,c] + sum_t k[c,t]*x[n-8+t, c]   (bf16 in/out). grid = (C/64, N/32)
__global__ __launch_bounds__(256) void dwconv_bf16(
    const u16* __restrict__ xin, int ldin, const float* __restrict__ kern,
    u16* __restrict__ y, int ldout, int N)
{
  __shared__ float tile[48][64];
  int c0 = blockIdx.x * 64;
  int n0 = blockIdx.y * 32;
  int t = threadIdx.x;
  int tx = t & 63, ty = t >> 6;
  #pragma unroll
  for (int it = 0; it < 12; ++it) {
    int idx = t + it*256;
    int r = idx >> 6, c = idx & 63;
    int gn = n0 - 8 + r;
    tile[r][c] = (gn >= 0 && gn < N) ? bf2f(xin[(long long)gn*ldin + c0 + c]) : 0.0f;
  }
  __syncthreads();
  int ch = c0 + tx;
  float kr[17];
  #pragma unroll
  for (int k = 0; k < 17; ++k) kr[k] = kern[ch*17 + k];
  #pragma unroll
  for (int rr = 0; rr < 8; ++rr) {
    int r = ty*8 + rr;
    float s = 0.0f;
    #pragma unroll
    for (int k = 0; k < 17; ++k) s = fmaf(kr[k], tile[r+k][tx], s);
    y[(long long)(n0 + r)*ldout + ch] = f2bf(tile[r+8][tx] + s);
  }
}

// final: out[n,c] = resid[n,c] + x[n,c] + conv(x)[n,c]  (bf16 in, fp32 resid/out, C=512)
__global__ __launch_bounds__(256) void dwconv_final(
    const u16* __restrict__ xin, const float* __restrict__ kern,
    const float* __restrict__ resid, float* __restrict__ y, int N)
{
  __shared__ float tile[48][64];
  int c0 = blockIdx.x * 64;
  int n0 = blockIdx.y * 32;
  int t = threadIdx.x;
  int tx = t & 63, ty = t >> 6;
  #pragma unroll
  for (int it = 0; it < 12; ++it) {
    int idx = t + it*256;
    int r = idx >> 6, c = idx & 63;
    int gn = n0 - 8 + r;
    tile[r][c] = (gn >= 0 && gn < N) ? bf2f(xin[(long long)gn*512 + c0 + c]) : 0.0f;
  }
  __syncthreads();
  int ch = c0 + tx;
  float kr[17];
  #pragma unroll
  for (int k = 0; k < 17; ++k) kr[k] = kern[ch*17 + k];
  #pragma unroll
  for (int rr = 0; rr < 8; ++rr) {
    int r = ty*8 + rr;
    float s = 0.0f;
    #pragma unroll
    for (int k = 0; k < 17; ++k) s = fmaf(kr[k], tile[r+k][tx], s);
    long long gi = (long long)(n0 + r)*512 + ch;
    y[gi] = resid[gi] + tile[r+8][tx] + s;
  }
}

__global__ void zero_kernel(float* __restrict__ p, long long total){
  long long i = (long long)blockIdx.x*256 + threadIdx.x;
  if (i < total) p[i] = 0.0f;
}

// F[d,e] += inv_n * sum_n (qk[n,d]*g3[d]+b3[d]) * h[n,e]   (atomic split over N)
__global__ __launch_bounds__(256) void linkv_kernel(
    const u16* __restrict__ qk, const float* __restrict__ osg, const float* __restrict__ osb,
    const u16* __restrict__ h, float* __restrict__ F, float inv_n, int N)
{
  __shared__ float Aq[32][128];
  __shared__ float Bh[32][128];
  __shared__ float g3s[128], b3s[128];
  int e0 = blockIdx.x * 128;
  int chunks_total = N / 32;
  int nper = chunks_total / gridDim.y;
  int c0 = blockIdx.y * nper;
  int t = threadIdx.x, tx = t & 15, ty = t >> 4;
  if (t < 128) { g3s[t] = osg[3*128+t]; b3s[t] = osb[3*128+t]; }
  __syncthreads();
  float acc[8][8] = {};
  for (int ch = 0; ch < nper; ++ch) {
    long long nb = (long long)(c0 + ch) * 32;
    __syncthreads();
    #pragma unroll
    for (int it = 0; it < 16; ++it) {
      int idx = t + it*256;
      int r = idx >> 7, d = idx & 127;
      Aq[r][d] = fmaf(bf2f(qk[(nb + r)*128 + d]), g3s[d], b3s[d]);
    }
    #pragma unroll
    for (int it = 0; it < 16; ++it) {
      int idx = t + it*256;
      int r = idx >> 7, e = idx & 127;
      Bh[r][e] = bf2f(h[(nb + r)*2048 + e0 + e]);
    }
    __syncthreads();
    #pragma unroll
    for (int nn = 0; nn < 32; ++nn) {
      float a[8], b[8];
      #pragma unroll
      for (int i = 0; i < 8; ++i) a[i] = Aq[nn][ty*8+i];
      #pragma unroll
      for (int j = 0; j < 8; ++j) b[j] = Bh[nn][tx*8+j];
      #pragma unroll
      for (int i = 0; i < 8; ++i)
        #pragma unroll
        for (int j = 0; j < 8; ++j)
          acc[i][j] = fmaf(a[i], b[j], acc[i][j]);
    }
  }
  #pragma unroll
  for (int i = 0; i < 8; ++i)
    #pragma unroll
    for (int j = 0; j < 8; ++j)
      atomicAdd(&F[(long long)(ty*8+i)*2048 + e0 + tx*8+j], acc[i][j]*inv_n);
}

// attn[g,i,j] = relu(qq[g,i,:].kk[g,j,:] / GS)^2  -> bf16
__global__ __launch_bounds__(256) void score_kernel(
    const u16* __restrict__ qk, const float* __restrict__ osg,
    const float* __restrict__ osb, u16* __restrict__ attn)
{
  __shared__ float qs[32][129];
  __shared__ float ks[64][129];
  int g = blockIdx.y;
  int i0 = blockIdx.x * 32;
  int t = threadIdx.x;
  int tx = t & 15, ty = t >> 4;
  #pragma unroll
  for (int it = 0; it < 16; ++it) {
    int idx = t + it*256;
    int r = idx >> 7, d = idx & 127;
    float v = bf2f(qk[((long long)(g*GSZ + i0 + r))*128 + d]);
    qs[r][d] = fmaf(v, osg[d], osb[d]);                 // quad_q (row 0)
  }
  for (int jc = 0; jc < 4; ++jc) {
    __syncthreads();
    #pragma unroll
    for (int it = 0; it < 32; ++it) {
      int idx = t + it*256;
      int r = idx >> 7, d = idx & 127;
      float v = bf2f(qk[((long long)(g*GSZ + jc*64 + r))*128 + d]);
      ks[r][d] = fmaf(v, osg[2*128+d], osb[2*128+d]);   // quad_k (row 2)
    }
    __syncthreads();
    float acc[2][4] = {};
    for (int d = 0; d < 128; ++d) {
      float a0 = qs[ty*2+0][d], a1 = qs[ty*2+1][d];
      float b0 = ks[tx*4+0][d], b1 = ks[tx*4+1][d];
      float b2 = ks[tx*4+2][d], b3 = ks[tx*4+3][d];
      acc[0][0] = fmaf(a0,b0,acc[0][0]); acc[0][1] = fmaf(a0,b1,acc[0][1]);
      acc[0][2] = fmaf(a0,b2,acc[0][2]); acc[0][3] = fmaf(a0,b3,acc[0][3]);
      acc[1][0] = fmaf(a1,b0,acc[1][0]); acc[1][1] = fmaf(a1,b1,acc[1][1]);
      acc[1][2] = fmaf(a1,b2,acc[1][2]); acc[1][3] = fmaf(a1,b3,acc[1][3]);
    }
    #pragma unroll
    for (int i = 0; i < 2; ++i) {
      ushort4 o;
      float r0 = fmaxf(acc[i][0]*(1.0f/GSZ), 0.0f);
      float r1 = fmaxf(acc[i][1]*(1.0f/GSZ), 0.0f);
      float r2 = fmaxf(acc[i][2]*(1.0f/GSZ), 0.0f);
      float r3 = fmaxf(acc[i][3]*(1.0f/GSZ), 0.0f);
      o.x = f2bf(r0*r0); o.y = f2bf(r1*r1); o.z = f2bf(r2*r2); o.w = f2bf(r3*r3);
      *(ushort4*)(attn + ((long long)(g*GSZ + i0 + ty*2 + i))*GSZ + jc*64 + tx*4) = o;
    }
  }
}

// fused: T2[n,c] = AU*v*sigm(AV*u), AV/AU = attn@h + linq@Flin for both halves.
// grid = (1024/64, GSZ/64, G)
__global__ __launch_bounds__(256) void quadlin_gate_kernel(
    const u16* __restrict__ attn, const u16* __restrict__ h,
    const u16* __restrict__ eqk,
    const float* __restrict__ osg, const float* __restrict__ osb,
    const float* __restrict__ Flin, u16* __restrict__ T2)
{
  int g = blockIdx.z;
  int bm = blockIdx.y * 64;
  int bn = blockIdx.x * 64;
  long long rowbase = (long long)g * GSZ;
  __shared__ float As[16][65];
  __shared__ float Bv[16][64];
  __shared__ float Bu[16][64];
  int t = threadIdx.x, tx = t & 15, ty = t >> 4;
  float accV[4][4] = {}, accU[4][4] = {};
  // phase 1: quad attention, K = 256
  for (int k0 = 0; k0 < GSZ; k0 += 16) {
    #pragma unroll
    for (int i = 0; i < 4; ++i) {
      int idx = t + i*256;
      int r = idx >> 4, c = idx & 15;
      As[c][r] = bf2f(attn[(rowbase + bm + r)*GSZ + k0 + c]);
    }
    #pragma unroll
    for (int i = 0; i < 4; ++i) {
      int idx = t + i*256;
      int r = idx >> 6, c = idx & 63;
      Bv[r][c] = bf2f(h[(rowbase + k0 + r)*2048 + bn + c]);
      Bu[r][c] = bf2f(h[(rowbase + k0 + r)*2048 + 1024 + bn + c]);
    }
    __syncthreads();
    #pragma unroll
    for (int kk = 0; kk < 16; ++kk) {
      float a[4], bv[4], bu[4];
      #pragma unroll
      for (int i = 0; i < 4; ++i) a[i] = As[kk][ty*4+i];
      #pragma unroll
      for (int j = 0; j < 4; ++j) { bv[j] = Bv[kk][tx*4+j]; bu[j] = Bu[kk][tx*4+j]; }
      #pragma unroll
      for (int i = 0; i < 4; ++i)
        #pragma unroll
        for (int j = 0; j < 4; ++j) {
          accV[i][j] = fmaf(a[i], bv[j], accV[i][j]);
          accU[i][j] = fmaf(a[i], bu[j], accU[i][j]);
        }
    }
    __syncthreads();
  }
  // phase 2: linear attention, K = 128, A = eqk*g1+b1
  for (int k0 = 0; k0 < 128; k0 += 16) {
    #pragma unroll
    for (int i = 0; i < 4; ++i) {
      int idx = t + i*256;
      int r = idx >> 4, c = idx & 15;
      int d = k0 + c;
      As[c][r] = fmaf(bf2f(eqk[(rowbase + bm + r)*128 + d]), osg[128+d], osb[128+d]);
    }
    #pragma unroll
    for (int i = 0; i < 4; ++i) {
      int idx = t + i*256;
      int r = idx >> 6, c = idx & 63;
      Bv[r][c] = Flin[(k0 + r)*2048 + bn + c];
      Bu[r][c] = Flin[(k0 + r)*2048 + 1024 + bn + c];
    }
    __syncthreads();
    #pragma unroll
    for (int kk = 0; kk < 16; ++kk) {
      float a[4], bv[4], bu[4];
      #pragma unroll
      for (int i = 0; i < 4; ++i) a[i] = As[kk][ty*4+i];
      #pragma unroll
      for (int j = 0; j < 4; ++j) { bv[j] = Bv[kk][tx*4+j]; bu[j] = Bu[kk][tx*4+j]; }
      #pragma unroll
      for (int i = 0; i < 4; ++i)
        #pragma unroll
        for (int j = 0; j < 4; ++j) {
          accV[i][j] = fmaf(a[i], bv[j], accV[i][j]);
          accU[i][j] = fmaf(a[i], bu[j], accU[i][j]);
        }
    }
    __syncthreads();
  }
  // epilogue: gate
  #pragma unroll
  for (int i = 0; i < 4; ++i) {
    long long n = rowbase + bm + ty*4 + i;
    ushort4 st;
    u16 sv[4];
    #pragma unroll
    for (int j = 0; j < 4; ++j) {
      int c = bn + tx*4 + j;
      float v = bf2f(h[n*2048 + c]);
      float u = bf2f(h[n*2048 + 1024 + c]);
      sv[j] = f2bf(accU[i][j] * v * sigm(accV[i][j] * u));
    }
    st.x = sv[0]; st.y = sv[1]; st.z = sv[2]; st.w = sv[3];
    *(ushort4*)(T2 + n*1024 + bn + tx*4) = st;
  }
}

// in-place layernorm over 1024 cols (stride 1024, bf16)
__global__ __launch_bounds__(256) void ln1024_kernel(u16* __restrict__ buf)
{
  long long n = blockIdx.x;
  ushort4* p = (ushort4*)(buf + n*1024) + threadIdx.x;
  ushort4 q = *p;
  float a = bf2f(q.x), b = bf2f(q.y), c = bf2f(q.z), d = bf2f(q.w);
  float s = a+b+c+d;
  float ss = fmaf(a,a, fmaf(b,b, fmaf(c,c, d*d)));
  float2 r = blockReduce2(s, ss);
  float mu = r.x * (1.0f/1024.0f);
  float var = r.y * (1.0f/1024.0f) - mu*mu;
  float rs = rsqrtf(var + 1e-5f);
  q.x = f2bf((a-mu)*rs); q.y = f2bf((b-mu)*rs);
  q.z = f2bf((c-mu)*rs); q.w = f2bf((d-mu)*rs);
  *p = q;
}

extern "C" void kernel_launch(void* const* d_in, const int* in_sizes, int n_in,
                              void* d_out, int out_size, void* d_ws, size_t ws_size,
                              hipStream_t stream)
{
  const float* x        = (const float*)d_in[0];
  const float* th_ln_g  = (const float*)d_in[2];
  const float* th_ln_b  = (const float*)d_in[3];
  const float* th_w     = (const float*)d_in[4];
  const float* th_b     = (const float*)d_in[5];
  const float* th_conv  = (const float*)d_in[6];
  const float* qk_ln_g  = (const float*)d_in[7];
  const float* qk_ln_b  = (const float*)d_in[8];
  const float* qk_w     = (const float*)d_in[9];
  const float* qk_b     = (const float*)d_in[10];
  const float* qk_conv  = (const float*)d_in[11];
  const float* osg      = (const float*)d_in[12];
  const float* osb      = (const float*)d_in[13];
  const float* out_ln_g = (const float*)d_in[14];
  const float* out_ln_b = (const float*)d_in[15];
  const float* out_w    = (const float*)d_in[16];
  const float* out_b    = (const float*)d_in[17];
  const float* out_conv = (const float*)d_in[18];

  const int N = in_sizes[0] / 512;          // 16384
  const float inv_n = 1.0f / (float)N;
  const int G = N / GSZ;                    // 64
  char* wsb = (char*)d_ws;

  // ---- workspace layout (bytes), lifetime-aliased ----
  size_t o_h    = 0;                                    // h bf16: N*2048
  size_t o_T2   = o_h   + (size_t)N*2048*2;             // T2 bf16: N*1024  (nx aliases front half)
  size_t o_sc   = o_T2  + (size_t)N*1024*2;             // scratch: tmpHpre(N*512)/Hattn(N*256)/outtmp(N*512) bf16
  size_t o_eqk  = o_sc  + (size_t)N*512*2;              // Eqk bf16: N*128
  size_t dq_sz  = (size_t)N*128*2;
  size_t fl_sz  = (size_t)128*2048*4;
  size_t o_dqk  = o_eqk + (size_t)N*128*2;              // Dqk bf16 (aliases Flin fp32)
  size_t o_wth  = o_dqk + (dq_sz > fl_sz ? dq_sz : fl_sz);
  size_t o_wqk  = o_wth + (size_t)512*2048*2;
  size_t o_wout = o_wqk + (size_t)512*128*2;
  size_t o_bth  = o_wout+ (size_t)1024*512*2;
  size_t o_bqk  = o_bth + 2048*4;
  size_t o_bout = o_bqk + 128*4;
  size_t required = o_bout + 512*4;
  if (ws_size < required) return;   // graceful failure (diagnosable), not a GPU fault

  u16*   h    = (u16*)(wsb + o_h);
  u16*   T2   = (u16*)(wsb + o_T2);
  u16*   nx   = T2;                 // alias: nx dead before T2 written
  u16*   scC  = (u16*)(wsb + o_sc);
  u16*   Eqk  = (u16*)(wsb + o_eqk);
  u16*   Dqk  = (u16*)(wsb + o_dqk);
  float* Flin = (float*)(wsb + o_dqk);  // alias: Dqk dead before Flin written
  u16*   Wth  = (u16*)(wsb + o_wth);
  u16*   Wqk  = (u16*)(wsb + o_wqk);
  u16*   Wout = (u16*)(wsb + o_wout);
  float* Bth  = (float*)(wsb + o_bth);
  float* Bqk  = (float*)(wsb + o_bqk);
  float* Bout = (float*)(wsb + o_bout);

  // ---- weight fusion (fold LN gamma/beta into weights/bias) ----
  hipLaunchKernelGGL(fuse_w_kernel, dim3(4096), dim3(256), 0, stream, th_ln_g, th_w, Wth, 2048, (long long)512*2048);
  hipLaunchKernelGGL(fuse_b_kernel, dim3(8),    dim3(256), 0, stream, th_ln_b, th_w, th_b, Bth, 512, 2048);
  hipLaunchKernelGGL(fuse_w_kernel, dim3(256),  dim3(256), 0, stream, qk_ln_g, qk_w, Wqk, 128, (long long)512*128);
  hipLaunchKernelGGL(fuse_b_kernel, dim3(1),    dim3(256), 0, stream, qk_ln_b, qk_w, qk_b, Bqk, 512, 128);
  hipLaunchKernelGGL(fuse_w_kernel, dim3(2048), dim3(256), 0, stream, out_ln_g, out_w, Wout, 512, (long long)1024*512);
  hipLaunchKernelGGL(fuse_b_kernel, dim3(2),    dim3(256), 0, stream, out_ln_b, out_w, out_b, Bout, 1024, 512);

  // ---- token shift + LN core ----
  hipLaunchKernelGGL(shift_ln_kernel, dim3(N), dim3(256), 0, stream, x, nx, N);

  // ---- th branch, chunked over 4 column chunks of 512 ----
  for (int ch = 0; ch < 4; ++ch) {
    hipLaunchKernelGGL(gemm_bf16, dim3(8, N/64), dim3(256), 0, stream,
                       nx, 512, Wth, 2048, ch*512, scC, 512, Bth, 512);
    hipLaunchKernelGGL(dwconv_bf16, dim3(8, N/32), dim3(256), 0, stream,
                       scC, 512, th_conv + (size_t)ch*512*17, h + (size_t)ch*512, 2048, N);
  }

  // ---- qk branch ----
  hipLaunchKernelGGL(gemm_bf16, dim3(2, N/64), dim3(256), 0, stream,
                     nx, 512, Wqk, 128, 0, Dqk, 128, Bqk, 512);
  hipLaunchKernelGGL(dwconv_bf16, dim3(2, N/32), dim3(256), 0, stream,
                     Dqk, 128, qk_conv, Eqk, 128, N);

  // ---- linear attention kv summary ----
  hipLaunchKernelGGL(zero_kernel, dim3(1024), dim3(256), 0, stream, Flin, (long long)128*2048);
  hipLaunchKernelGGL(linkv_kernel, dim3(16, 32), dim3(256), 0, stream, Eqk, osg, osb, h, Flin, inv_n, N);

  // ---- quadratic attention scores (into scratch, tmpHpre dead) ----
  hipLaunchKernelGGL(score_kernel, dim3(8, G), dim3(256), 0, stream, Eqk, osg, osb, scC);

  // ---- fused quad + lin + gate -> T2 (N x 1024) ----
  hipLaunchKernelGGL(quadlin_gate_kernel, dim3(16, GSZ/64, G), dim3(256), 0, stream,
                     scC, h, Eqk, osg, osb, Flin, T2);

  // ---- out branch: LN in place, GEMM to 512 (into scratch), final residual conv ----
  hipLaunchKernelGGL(ln1024_kernel, dim3(N), dim3(256), 0, stream, T2);
  hipLaunchKernelGGL(gemm_bf16, dim3(8, N/64), dim3(256), 0, stream,
                     T2, 1024, Wout, 512, 0, scC, 512, Bout, 1024);
  hipLaunchKernelGGL(dwconv_final, dim3(8, N/32), dim3(256), 0, stream,
                     scC, out_conv, x, (float*)d_out, N);
}

// Round 3
// 872.190 us; speedup vs baseline: 2.4045x; 2.4045x over previous
//
#include <hip/hip_runtime.h>
#include <math.h>

#define GSZ 256

typedef unsigned short u16;
typedef short bf16x8 __attribute__((ext_vector_type(8)));
typedef float f32x4 __attribute__((ext_vector_type(4)));
#define MFMA16 __builtin_amdgcn_mfma_f32_16x16x32_bf16

__device__ __forceinline__ float bf2f(u16 u){
  union { unsigned int i; float f; } x; x.i = ((unsigned int)u) << 16; return x.f;
}
__device__ __forceinline__ u16 f2bf(float f){
  union { float ff; unsigned int i; } x; x.ff = f;
  unsigned int r = x.i + 0x7fffu + ((x.i >> 16) & 1u);
  return (u16)(r >> 16);
}
__device__ __forceinline__ float sigm(float x){ return 1.0f/(1.0f+__expf(-x)); }
__device__ __forceinline__ float siluf(float x){ return x/(1.0f+__expf(-x)); }

__device__ __forceinline__ float2 blockReduce2(float s, float ss){
  __shared__ float red[8];
  #pragma unroll
  for (int off=32; off>0; off>>=1){
    s  += __shfl_down(s, off, 64);
    ss += __shfl_down(ss, off, 64);
  }
  int lane = threadIdx.x & 63, wid = threadIdx.x >> 6;
  if (lane==0){ red[wid]=s; red[4+wid]=ss; }
  __syncthreads();
  float2 r;
  r.x = red[0]+red[1]+red[2]+red[3];
  r.y = red[4]+red[5]+red[6]+red[7];
  return r;
}

// ---------------- small prep kernels ----------------

__global__ __launch_bounds__(256) void shift_ln_kernel(
    const float* __restrict__ x, u16* __restrict__ out, int N)
{
  int n = blockIdx.x;
  int t = threadIdx.x;
  float v0 = (n > 0) ? x[(long long)(n-1)*512 + t] : 0.0f;
  float v1 = x[(long long)n*512 + 256 + t];
  float2 r = blockReduce2(v0+v1, fmaf(v0,v0,v1*v1));
  float mu = r.x * (1.0f/512.0f);
  float var = r.y * (1.0f/512.0f) - mu*mu;
  float rs = rsqrtf(var + 1e-5f);
  long long base = (long long)n*512;
  out[base + t]       = f2bf((v0-mu)*rs);
  out[base + 256 + t] = f2bf((v1-mu)*rs);
}

// WT[n][k] = g[k]*W[k][n] -> bf16.  grid (K/32, Nn/32), 256 thr
__global__ __launch_bounds__(256) void fuse_wT_kernel(
    const float* __restrict__ g, const float* __restrict__ w,
    u16* __restrict__ wT, int K, int Nn)
{
  __shared__ float sL[32][33];
  int k0 = blockIdx.x*32, n0 = blockIdx.y*32;
  int t = threadIdx.x;
  int r = t >> 3, cq = t & 7;
  float4 v = *(const float4*)(w + (size_t)(k0+r)*Nn + n0 + cq*4);
  float gg = g[k0+r];
  sL[r][cq*4+0] = v.x*gg; sL[r][cq*4+1] = v.y*gg;
  sL[r][cq*4+2] = v.z*gg; sL[r][cq*4+3] = v.w*gg;
  __syncthreads();
  ushort4 o;
  o.x = f2bf(sL[cq*4+0][r]); o.y = f2bf(sL[cq*4+1][r]);
  o.z = f2bf(sL[cq*4+2][r]); o.w = f2bf(sL[cq*4+3][r]);
  *(ushort4*)(wT + (size_t)(n0+r)*K + k0 + cq*4) = o;
}

// b'[n] = bias[n] + sum_k b_ln[k]*W[k,n]
__global__ void fuse_b_kernel(const float* __restrict__ bln, const float* __restrict__ w,
                              const float* __restrict__ bias, float* __restrict__ bout,
                              int K, int Nn)
{
  int nid = blockIdx.x*256 + threadIdx.x;
  if (nid < Nn) {
    float acc = bias[nid];
    for (int k = 0; k < K; ++k) acc = fmaf(bln[k], w[(long long)k*Nn + nid], acc);
    bout[nid] = acc;
  }
}

__global__ void zero_kernel(float* __restrict__ p, long long total){
  long long i = (long long)blockIdx.x*256 + threadIdx.x;
  if (i < total) p[i] = 0.0f;
}

// ---------------- MFMA GEMM kernels ----------------
// Tile: BM=128, BN=64, BK=32. 4 waves; wave w: (wm=w>>1)*64 rows, (wn=w&1)*32 cols.
// Frags: A row=l&15 k=(l>>4)*8+j ; B col=l&15 ; D col=l&15 row=(l>>4)*4+i.
// LDS layout frag-major units of 16B: A [4][129], B [4][65] (padded, conflict-free).

// C = silu(A @ WT^T + bias)
__global__ __launch_bounds__(256) void gemm_mfma_silu(
    const u16* __restrict__ A, int lda,
    const u16* __restrict__ BT, int ldbt, int wtc0,
    u16* __restrict__ C, int ldc,
    const float* __restrict__ bias, int K)
{
  __shared__ bf16x8 Al[4*129];
  __shared__ bf16x8 Bl[4*65];
  int t = threadIdx.x;
  int lane = t & 63, wid = t >> 6;
  int wm = wid >> 1, wn = wid & 1;
  int lrow = lane & 15, kcL = lane >> 4;
  int bm = blockIdx.y * 128, bn = blockIdx.x * 64;
  f32x4 acc[4][2] = {};
  for (int k0 = 0; k0 < K; k0 += 32) {
    #pragma unroll
    for (int i = 0; i < 2; ++i) {
      int u = t + i*256;
      int r = u >> 2, kc = u & 3;
      Al[kc*129 + r] = *(const bf16x8*)(A + (size_t)(bm + r)*lda + k0 + kc*8);
    }
    {
      int col = t >> 2, kc = t & 3;
      Bl[kc*65 + col] = *(const bf16x8*)(BT + (size_t)(wtc0 + bn + col)*ldbt + k0 + kc*8);
    }
    __syncthreads();
    bf16x8 af[4], bfr[2];
    #pragma unroll
    for (int mr = 0; mr < 4; ++mr) af[mr] = Al[kcL*129 + wm*64 + mr*16 + lrow];
    #pragma unroll
    for (int nr = 0; nr < 2; ++nr) bfr[nr] = Bl[kcL*65 + wn*32 + nr*16 + lrow];
    #pragma unroll
    for (int mr = 0; mr < 4; ++mr)
      #pragma unroll
      for (int nr = 0; nr < 2; ++nr)
        acc[mr][nr] = MFMA16(af[mr], bfr[nr], acc[mr][nr], 0, 0, 0);
    __syncthreads();
  }
  #pragma unroll
  for (int mr = 0; mr < 4; ++mr)
    #pragma unroll
    for (int nr = 0; nr < 2; ++nr) {
      int col = bn + wn*32 + nr*16 + lrow;
      float bs = bias[wtc0 + col];
      #pragma unroll
      for (int i = 0; i < 4; ++i) {
        int row = bm + wm*64 + mr*16 + kcL*4 + i;
        C[(size_t)row*ldc + col] = f2bf(siluf(acc[mr][nr][i] + bs));
      }
    }
}

// attn = relu(qq@kk^T/GS)^2 per group. grid (4, 2, G)
__global__ __launch_bounds__(256) void score_mfma(
    const u16* __restrict__ eqk, const float* __restrict__ osg,
    const float* __restrict__ osb, u16* __restrict__ attn)
{
  __shared__ bf16x8 Al[4*129];
  __shared__ bf16x8 Bl[4*65];
  int t = threadIdx.x;
  int lane = t & 63, wid = t >> 6;
  int wm = wid >> 1, wn = wid & 1;
  int lrow = lane & 15, kcL = lane >> 4;
  int g = blockIdx.z;
  int bm = blockIdx.y * 128, bn = blockIdx.x * 64;
  const u16* base = eqk + (size_t)g*GSZ*128;
  f32x4 acc[4][2] = {};
  for (int k0 = 0; k0 < 128; k0 += 32) {
    #pragma unroll
    for (int i = 0; i < 2; ++i) {
      int u = t + i*256;
      int r = u >> 2, kc = u & 3;
      bf16x8 raw = *(const bf16x8*)(base + (size_t)(bm + r)*128 + k0 + kc*8);
      bf16x8 v;
      #pragma unroll
      for (int j = 0; j < 8; ++j) {
        int kk = k0 + kc*8 + j;
        v[j] = (short)f2bf(fmaf(bf2f((u16)raw[j]), osg[kk], osb[kk]));   // quad_q row 0
      }
      Al[kc*129 + r] = v;
    }
    {
      int col = t >> 2, kc = t & 3;
      bf16x8 raw = *(const bf16x8*)(base + (size_t)(bn + col)*128 + k0 + kc*8);
      bf16x8 v;
      #pragma unroll
      for (int j = 0; j < 8; ++j) {
        int kk = k0 + kc*8 + j;
        v[j] = (short)f2bf(fmaf(bf2f((u16)raw[j]), osg[2*128+kk], osb[2*128+kk])); // quad_k row 2
      }
      Bl[kc*65 + col] = v;
    }
    __syncthreads();
    bf16x8 af[4], bfr[2];
    #pragma unroll
    for (int mr = 0; mr < 4; ++mr) af[mr] = Al[kcL*129 + wm*64 + mr*16 + lrow];
    #pragma unroll
    for (int nr = 0; nr < 2; ++nr) bfr[nr] = Bl[kcL*65 + wn*32 + nr*16 + lrow];
    #pragma unroll
    for (int mr = 0; mr < 4; ++mr)
      #pragma unroll
      for (int nr = 0; nr < 2; ++nr)
        acc[mr][nr] = MFMA16(af[mr], bfr[nr], acc[mr][nr], 0, 0, 0);
    __syncthreads();
  }
  #pragma unroll
  for (int mr = 0; mr < 4; ++mr)
    #pragma unroll
    for (int nr = 0; nr < 2; ++nr) {
      int col = bn + wn*32 + nr*16 + lrow;
      #pragma unroll
      for (int i = 0; i < 4; ++i) {
        int row = bm + wm*64 + mr*16 + kcL*4 + i;
        float s = fmaxf(acc[mr][nr][i] * (1.0f/GSZ), 0.0f);
        attn[((size_t)g*GSZ + row)*GSZ + col] = f2bf(s*s);
      }
    }
}

// F[d][e] += inv_n * sum_n (eqk[n,d]*g3+b3) * h[n,e].  grid (2048/64, 16)
__global__ __launch_bounds__(256) void linkv_mfma(
    const u16* __restrict__ eqk, const float* __restrict__ osg, const float* __restrict__ osb,
    const u16* __restrict__ h, float* __restrict__ F, float inv_n, int N)
{
  __shared__ bf16x8 Al[4*129];
  __shared__ bf16x8 Bl[4*65];
  int t = threadIdx.x;
  int lane = t & 63, wid = t >> 6;
  int wm = wid >> 1, wn = wid & 1;
  int lrow = lane & 15, kcL = lane >> 4;
  int e0 = blockIdx.x * 64;
  int Kslice = N / gridDim.y;
  int n0base = blockIdx.y * Kslice;
  f32x4 acc[4][2] = {};
  for (int k0 = 0; k0 < Kslice; k0 += 32) {
    int nb = n0base + k0;
    #pragma unroll
    for (int i = 0; i < 2; ++i) {
      int d = (t & 63) + i*64;
      int kc = t >> 6;
      float g3 = osg[3*128+d], b3 = osb[3*128+d];
      bf16x8 v;
      #pragma unroll
      for (int j = 0; j < 8; ++j)
        v[j] = (short)f2bf(fmaf(bf2f(eqk[(size_t)(nb + kc*8 + j)*128 + d]), g3, b3));
      Al[kc*129 + d] = v;
    }
    {
      int col = t & 63, kc = t >> 6;
      bf16x8 v;
      #pragma unroll
      for (int j = 0; j < 8; ++j)
        v[j] = (short)h[(size_t)(nb + kc*8 + j)*2048 + e0 + col];
      Bl[kc*65 + col] = v;
    }
    __syncthreads();
    bf16x8 af[4], bfr[2];
    #pragma unroll
    for (int mr = 0; mr < 4; ++mr) af[mr] = Al[kcL*129 + wm*64 + mr*16 + lrow];
    #pragma unroll
    for (int nr = 0; nr < 2; ++nr) bfr[nr] = Bl[kcL*65 + wn*32 + nr*16 + lrow];
    #pragma unroll
    for (int mr = 0; mr < 4; ++mr)
      #pragma unroll
      for (int nr = 0; nr < 2; ++nr)
        acc[mr][nr] = MFMA16(af[mr], bfr[nr], acc[mr][nr], 0, 0, 0);
    __syncthreads();
  }
  #pragma unroll
  for (int mr = 0; mr < 4; ++mr)
    #pragma unroll
    for (int nr = 0; nr < 2; ++nr) {
      int e = e0 + wn*32 + nr*16 + lrow;
      #pragma unroll
      for (int i = 0; i < 4; ++i) {
        int d = wm*64 + mr*16 + kcL*4 + i;
        atomicAdd(&F[(size_t)d*2048 + e], acc[mr][nr][i]*inv_n);
      }
    }
}

// FTg[e][d] = g1[d]*F[d][e] (bf16) ; cvec[e] = sum_d b1[d]*F[d][e]
__global__ __launch_bounds__(256) void fconv_kernel(
    const float* __restrict__ F, const float* __restrict__ osg, const float* __restrict__ osb,
    u16* __restrict__ FTg, float* __restrict__ cvec)
{
  __shared__ float g1s[128], b1s[128];
  int t = threadIdx.x;
  if (t < 128) { g1s[t] = osg[128+t]; b1s[t] = osb[128+t]; }
  __syncthreads();
  int e = blockIdx.x*256 + t;
  float c = 0.f;
  for (int d = 0; d < 128; ++d) {
    float f = F[(size_t)d*2048 + e];
    c = fmaf(b1s[d], f, c);
    FTg[(size_t)e*128 + d] = f2bf(g1s[d] * f);
  }
  cvec[e] = c;
}

// fused quad+lin attention + gate.  grid (1024/64, 2, G)
__global__ __launch_bounds__(256) void quadlin_mfma(
    const u16* __restrict__ attn, const u16* __restrict__ h,
    const u16* __restrict__ eqk, const u16* __restrict__ FTg,
    const float* __restrict__ cvec, u16* __restrict__ T2)
{
  __shared__ bf16x8 Al[4*129];
  __shared__ bf16x8 Bv[4*65];
  __shared__ bf16x8 Bu[4*65];
  int t = threadIdx.x;
  int lane = t & 63, wid = t >> 6;
  int wm = wid >> 1, wn = wid & 1;
  int lrow = lane & 15, kcL = lane >> 4;
  int g = blockIdx.z;
  int bm = blockIdx.y * 128, cb = blockIdx.x * 64;
  size_t rowbase = (size_t)g * GSZ;
  f32x4 accV[4][2] = {}, accU[4][2] = {};
  // phase 1: quad attention, K=256, B = h columns
  for (int k0 = 0; k0 < GSZ; k0 += 32) {
    #pragma unroll
    for (int i = 0; i < 2; ++i) {
      int u = t + i*256;
      int r = u >> 2, kc = u & 3;
      Al[kc*129 + r] = *(const bf16x8*)(attn + ((size_t)(rowbase + bm + r))*GSZ + k0 + kc*8);
    }
    {
      int col = t & 63, kc = t >> 6;
      bf16x8 vv, uu;
      #pragma unroll
      for (int j = 0; j < 8; ++j) {
        size_t hrow = (rowbase + k0 + kc*8 + j)*2048;
        vv[j] = (short)h[hrow + cb + col];
        uu[j] = (short)h[hrow + 1024 + cb + col];
      }
      Bv[kc*65 + col] = vv;
      Bu[kc*65 + col] = uu;
    }
    __syncthreads();
    bf16x8 af[4], bv[2], bu[2];
    #pragma unroll
    for (int mr = 0; mr < 4; ++mr) af[mr] = Al[kcL*129 + wm*64 + mr*16 + lrow];
    #pragma unroll
    for (int nr = 0; nr < 2; ++nr) { bv[nr] = Bv[kcL*65 + wn*32 + nr*16 + lrow];
                                     bu[nr] = Bu[kcL*65 + wn*32 + nr*16 + lrow]; }
    #pragma unroll
    for (int mr = 0; mr < 4; ++mr)
      #pragma unroll
      for (int nr = 0; nr < 2; ++nr) {
        accV[mr][nr] = MFMA16(af[mr], bv[nr], accV[mr][nr], 0, 0, 0);
        accU[mr][nr] = MFMA16(af[mr], bu[nr], accU[mr][nr], 0, 0, 0);
      }
    __syncthreads();
  }
  // phase 2: linear attention, K=128, A = raw eqk rows, B = FTg rows (g1 folded, b1 in cvec)
  for (int k0 = 0; k0 < 128; k0 += 32) {
    #pragma unroll
    for (int i = 0; i < 2; ++i) {
      int u = t + i*256;
      int r = u >> 2, kc = u & 3;
      Al[kc*129 + r] = *(const bf16x8*)(eqk + (rowbase + bm + r)*128 + k0 + kc*8);
    }
    {
      int col = t >> 2, kc = t & 3;
      Bv[kc*65 + col] = *(const bf16x8*)(FTg + (size_t)(cb + col)*128 + k0 + kc*8);
      Bu[kc*65 + col] = *(const bf16x8*)(FTg + (size_t)(1024 + cb + col)*128 + k0 + kc*8);
    }
    __syncthreads();
    bf16x8 af[4], bv[2], bu[2];
    #pragma unroll
    for (int mr = 0; mr < 4; ++mr) af[mr] = Al[kcL*129 + wm*64 + mr*16 + lrow];
    #pragma unroll
    for (int nr = 0; nr < 2; ++nr) { bv[nr] = Bv[kcL*65 + wn*32 + nr*16 + lrow];
                                     bu[nr] = Bu[kcL*65 + wn*32 + nr*16 + lrow]; }
    #pragma unroll
    for (int mr = 0; mr < 4; ++mr)
      #pragma unroll
      for (int nr = 0; nr < 2; ++nr) {
        accV[mr][nr] = MFMA16(af[mr], bv[nr], accV[mr][nr], 0, 0, 0);
        accU[mr][nr] = MFMA16(af[mr], bu[nr], accU[mr][nr], 0, 0, 0);
      }
    __syncthreads();
  }
  // epilogue: gate
  #pragma unroll
  for (int mr = 0; mr < 4; ++mr)
    #pragma unroll
    for (int nr = 0; nr < 2; ++nr) {
      int c = cb + wn*32 + nr*16 + lrow;
      float cV = cvec[c], cU = cvec[1024 + c];
      #pragma unroll
      for (int i = 0; i < 4; ++i) {
        size_t n = rowbase + bm + wm*64 + mr*16 + kcL*4 + i;
        float v = bf2f(h[n*2048 + c]);
        float u = bf2f(h[n*2048 + 1024 + c]);
        float av = accV[mr][nr][i] + cV;
        float au = accU[mr][nr][i] + cU;
        T2[n*1024 + c] = f2bf(au * v * sigm(av * u));
      }
    }
}

// ---------------- conv / norm kernels (unchanged) ----------------

__global__ __launch_bounds__(256) void dwconv_bf16(
    const u16* __restrict__ xin, int ldin, const float* __restrict__ kern,
    u16* __restrict__ y, int ldout, int N)
{
  __shared__ float tile[48][64];
  int c0 = blockIdx.x * 64;
  int n0 = blockIdx.y * 32;
  int t = threadIdx.x;
  int tx = t & 63, ty = t >> 6;
  #pragma unroll
  for (int it = 0; it < 12; ++it) {
    int idx = t + it*256;
    int r = idx >> 6, c = idx & 63;
    int gn = n0 - 8 + r;
    tile[r][c] = (gn >= 0 && gn < N) ? bf2f(xin[(long long)gn*ldin + c0 + c]) : 0.0f;
  }
  __syncthreads();
  int ch = c0 + tx;
  float kr[17];
  #pragma unroll
  for (int k = 0; k < 17; ++k) kr[k] = kern[ch*17 + k];
  #pragma unroll
  for (int rr = 0; rr < 8; ++rr) {
    int r = ty*8 + rr;
    float s = 0.0f;
    #pragma unroll
    for (int k = 0; k < 17; ++k) s = fmaf(kr[k], tile[r+k][tx], s);
    y[(long long)(n0 + r)*ldout + ch] = f2bf(tile[r+8][tx] + s);
  }
}

__global__ __launch_bounds__(256) void dwconv_final(
    const u16* __restrict__ xin, const float* __restrict__ kern,
    const float* __restrict__ resid, float* __restrict__ y, int N)
{
  __shared__ float tile[48][64];
  int c0 = blockIdx.x * 64;
  int n0 = blockIdx.y * 32;
  int t = threadIdx.x;
  int tx = t & 63, ty = t >> 6;
  #pragma unroll
  for (int it = 0; it < 12; ++it) {
    int idx = t + it*256;
    int r = idx >> 6, c = idx & 63;
    int gn = n0 - 8 + r;
    tile[r][c] = (gn >= 0 && gn < N) ? bf2f(xin[(long long)gn*512 + c0 + c]) : 0.0f;
  }
  __syncthreads();
  int ch = c0 + tx;
  float kr[17];
  #pragma unroll
  for (int k = 0; k < 17; ++k) kr[k] = kern[ch*17 + k];
  #pragma unroll
  for (int rr = 0; rr < 8; ++rr) {
    int r = ty*8 + rr;
    float s = 0.0f;
    #pragma unroll
    for (int k = 0; k < 17; ++k) s = fmaf(kr[k], tile[r+k][tx], s);
    long long gi = (long long)(n0 + r)*512 + ch;
    y[gi] = resid[gi] + tile[r+8][tx] + s;
  }
}

__global__ __launch_bounds__(256) void ln1024_kernel(u16* __restrict__ buf)
{
  long long n = blockIdx.x;
  ushort4* p = (ushort4*)(buf + n*1024) + threadIdx.x;
  ushort4 q = *p;
  float a = bf2f(q.x), b = bf2f(q.y), c = bf2f(q.z), d = bf2f(q.w);
  float s = a+b+c+d;
  float ss = fmaf(a,a, fmaf(b,b, fmaf(c,c, d*d)));
  float2 r = blockReduce2(s, ss);
  float mu = r.x * (1.0f/1024.0f);
  float var = r.y * (1.0f/1024.0f) - mu*mu;
  float rs = rsqrtf(var + 1e-5f);
  q.x = f2bf((a-mu)*rs); q.y = f2bf((b-mu)*rs);
  q.z = f2bf((c-mu)*rs); q.w = f2bf((d-mu)*rs);
  *p = q;
}

// ---------------- host launcher ----------------

extern "C" void kernel_launch(void* const* d_in, const int* in_sizes, int n_in,
                              void* d_out, int out_size, void* d_ws, size_t ws_size,
                              hipStream_t stream)
{
  const float* x        = (const float*)d_in[0];
  const float* th_ln_g  = (const float*)d_in[2];
  const float* th_ln_b  = (const float*)d_in[3];
  const float* th_w     = (const float*)d_in[4];
  const float* th_b     = (const float*)d_in[5];
  const float* th_conv  = (const float*)d_in[6];
  const float* qk_ln_g  = (const float*)d_in[7];
  const float* qk_ln_b  = (const float*)d_in[8];
  const float* qk_w     = (const float*)d_in[9];
  const float* qk_b     = (const float*)d_in[10];
  const float* qk_conv  = (const float*)d_in[11];
  const float* osg      = (const float*)d_in[12];
  const float* osb      = (const float*)d_in[13];
  const float* out_ln_g = (const float*)d_in[14];
  const float* out_ln_b = (const float*)d_in[15];
  const float* out_w    = (const float*)d_in[16];
  const float* out_b    = (const float*)d_in[17];
  const float* out_conv = (const float*)d_in[18];

  const int N = in_sizes[0] / 512;          // 16384
  const float inv_n = 1.0f / (float)N;
  const int G = N / GSZ;                    // 64
  char* wsb = (char*)d_ws;

  // ---- workspace layout (bytes), lifetime-aliased ----
  size_t o_h    = 0;                                    // h bf16: N*2048
  size_t o_T2   = o_h   + (size_t)N*2048*2;             // T2 bf16: N*1024 (nx aliases)
  size_t o_sc   = o_T2  + (size_t)N*1024*2;             // scratch bf16: N*512 (th tmp / attn / out tmp)
  size_t o_eqk  = o_sc  + (size_t)N*512*2;              // Eqk bf16: N*128
  size_t o_dqk  = o_eqk + (size_t)N*128*2;              // Dqk bf16 N*128 (aliases F/FTg/cvec)
  size_t dq_sz  = (size_t)N*128*2;                      // 4 MB
  size_t o_wth  = o_dqk + dq_sz;
  size_t o_wqk  = o_wth + (size_t)2048*512*2;           // WthT
  size_t o_wout = o_wqk + (size_t)128*512*2;            // WqkT
  size_t o_bth  = o_wout+ (size_t)512*1024*2;           // WoutT
  size_t o_bqk  = o_bth + 2048*4;
  size_t o_bout = o_bqk + 128*4;
  size_t required = o_bout + 512*4;
  if (ws_size < required) return;

  u16*   h    = (u16*)(wsb + o_h);
  u16*   T2   = (u16*)(wsb + o_T2);
  u16*   nx   = T2;                       // alias: nx dead before T2 written
  u16*   scC  = (u16*)(wsb + o_sc);
  u16*   Eqk  = (u16*)(wsb + o_eqk);
  u16*   Dqk  = (u16*)(wsb + o_dqk);
  float* F    = (float*)(wsb + o_dqk);                     // 128*2048*4 = 1 MB
  u16*   FTg  = (u16*)(wsb + o_dqk + (size_t)128*2048*4);  // 0.5 MB
  float* cvec = (float*)(wsb + o_dqk + (size_t)128*2048*4 + (size_t)2048*128*2);
  u16*   WthT = (u16*)(wsb + o_wth);
  u16*   WqkT = (u16*)(wsb + o_wqk);
  u16*   WoutT= (u16*)(wsb + o_wout);
  float* Bth  = (float*)(wsb + o_bth);
  float* Bqk  = (float*)(wsb + o_bqk);
  float* Bout = (float*)(wsb + o_bout);

  // ---- weight prep ----
  hipLaunchKernelGGL(fuse_wT_kernel, dim3(16, 64), dim3(256), 0, stream, th_ln_g, th_w, WthT, 512, 2048);
  hipLaunchKernelGGL(fuse_b_kernel,  dim3(8),      dim3(256), 0, stream, th_ln_b, th_w, th_b, Bth, 512, 2048);
  hipLaunchKernelGGL(fuse_wT_kernel, dim3(16, 4),  dim3(256), 0, stream, qk_ln_g, qk_w, WqkT, 512, 128);
  hipLaunchKernelGGL(fuse_b_kernel,  dim3(1),      dim3(256), 0, stream, qk_ln_b, qk_w, qk_b, Bqk, 512, 128);
  hipLaunchKernelGGL(fuse_wT_kernel, dim3(32, 16), dim3(256), 0, stream, out_ln_g, out_w, WoutT, 1024, 512);
  hipLaunchKernelGGL(fuse_b_kernel,  dim3(2),      dim3(256), 0, stream, out_ln_b, out_w, out_b, Bout, 1024, 512);

  // ---- token shift + LN core ----
  hipLaunchKernelGGL(shift_ln_kernel, dim3(N), dim3(256), 0, stream, x, nx, N);

  // ---- th branch, 4 column chunks of 512 ----
  for (int ch = 0; ch < 4; ++ch) {
    hipLaunchKernelGGL(gemm_mfma_silu, dim3(8, N/128), dim3(256), 0, stream,
                       nx, 512, WthT, 512, ch*512, scC, 512, Bth, 512);
    hipLaunchKernelGGL(dwconv_bf16, dim3(8, N/32), dim3(256), 0, stream,
                       scC, 512, th_conv + (size_t)ch*512*17, h + (size_t)ch*512, 2048, N);
  }

  // ---- qk branch ----
  hipLaunchKernelGGL(gemm_mfma_silu, dim3(2, N/128), dim3(256), 0, stream,
                     nx, 512, WqkT, 512, 0, Dqk, 128, Bqk, 512);
  hipLaunchKernelGGL(dwconv_bf16, dim3(2, N/32), dim3(256), 0, stream,
                     Dqk, 128, qk_conv, Eqk, 128, N);

  // ---- linear attention kv summary ----
  hipLaunchKernelGGL(zero_kernel, dim3(1024), dim3(256), 0, stream, F, (long long)128*2048);
  hipLaunchKernelGGL(linkv_mfma, dim3(32, 16), dim3(256), 0, stream, Eqk, osg, osb, h, F, inv_n, N);
  hipLaunchKernelGGL(fconv_kernel, dim3(8), dim3(256), 0, stream, F, osg, osb, FTg, cvec);

  // ---- quadratic attention scores -> scC ----
  hipLaunchKernelGGL(score_mfma, dim3(4, 2, G), dim3(256), 0, stream, Eqk, osg, osb, scC);

  // ---- fused quad + lin + gate -> T2 ----
  hipLaunchKernelGGL(quadlin_mfma, dim3(16, 2, G), dim3(256), 0, stream,
                     scC, h, Eqk, FTg, cvec, T2);

  // ---- out branch ----
  hipLaunchKernelGGL(ln1024_kernel, dim3(N), dim3(256), 0, stream, T2);
  hipLaunchKernelGGL(gemm_mfma_silu, dim3(8, N/128), dim3(256), 0, stream,
                     T2, 1024, WoutT, 1024, 0, scC, 512, Bout, 1024);
  hipLaunchKernelGGL(dwconv_final, dim3(8, N/32), dim3(256), 0, stream,
                     scC, out_conv, x, (float*)d_out, N);
}

// Round 4
// 478.383 us; speedup vs baseline: 4.3839x; 1.8232x over previous
//
#include <hip/hip_runtime.h>
#include <math.h>

#define GSZ 256

typedef unsigned short u16;
typedef short bf16x8 __attribute__((ext_vector_type(8)));
typedef float f32x4 __attribute__((ext_vector_type(4)));
#define MFMA16 __builtin_amdgcn_mfma_f32_16x16x32_bf16

__device__ __forceinline__ float bf2f(u16 u){
  union { unsigned int i; float f; } x; x.i = ((unsigned int)u) << 16; return x.f;
}
__device__ __forceinline__ u16 f2bf(float f){
  union { float ff; unsigned int i; } x; x.ff = f;
  unsigned int r = x.i + 0x7fffu + ((x.i >> 16) & 1u);
  return (u16)(r >> 16);
}
__device__ __forceinline__ float sigm(float x){ return 1.0f/(1.0f+__expf(-x)); }
__device__ __forceinline__ float siluf(float x){ return x/(1.0f+__expf(-x)); }

__device__ __forceinline__ float2 blockReduce2(float s, float ss){
  __shared__ float red[8];
  #pragma unroll
  for (int off=32; off>0; off>>=1){
    s  += __shfl_down(s, off, 64);
    ss += __shfl_down(ss, off, 64);
  }
  int lane = threadIdx.x & 63, wid = threadIdx.x >> 6;
  if (lane==0){ red[wid]=s; red[4+wid]=ss; }
  __syncthreads();
  float2 r;
  r.x = red[0]+red[1]+red[2]+red[3];
  r.y = red[4]+red[5]+red[6]+red[7];
  return r;
}

// ---------------- small prep kernels ----------------

__global__ __launch_bounds__(256) void shift_ln_kernel(
    const float* __restrict__ x, u16* __restrict__ out, int N)
{
  int n = blockIdx.x;
  int t = threadIdx.x;
  float v0 = (n > 0) ? x[(long long)(n-1)*512 + t] : 0.0f;
  float v1 = x[(long long)n*512 + 256 + t];
  float2 r = blockReduce2(v0+v1, fmaf(v0,v0,v1*v1));
  float mu = r.x * (1.0f/512.0f);
  float var = r.y * (1.0f/512.0f) - mu*mu;
  float rs = rsqrtf(var + 1e-5f);
  long long base = (long long)n*512;
  out[base + t]       = f2bf((v0-mu)*rs);
  out[base + 256 + t] = f2bf((v1-mu)*rs);
}

// WT[n][k] = g[k]*W[k][n] -> bf16.  grid (K/32, Nn/32), 256 thr
__global__ __launch_bounds__(256) void fuse_wT_kernel(
    const float* __restrict__ g, const float* __restrict__ w,
    u16* __restrict__ wT, int K, int Nn)
{
  __shared__ float sL[32][33];
  int k0 = blockIdx.x*32, n0 = blockIdx.y*32;
  int t = threadIdx.x;
  int r = t >> 3, cq = t & 7;
  float4 v = *(const float4*)(w + (size_t)(k0+r)*Nn + n0 + cq*4);
  float gg = g[k0+r];
  sL[r][cq*4+0] = v.x*gg; sL[r][cq*4+1] = v.y*gg;
  sL[r][cq*4+2] = v.z*gg; sL[r][cq*4+3] = v.w*gg;
  __syncthreads();
  ushort4 o;
  o.x = f2bf(sL[cq*4+0][r]); o.y = f2bf(sL[cq*4+1][r]);
  o.z = f2bf(sL[cq*4+2][r]); o.w = f2bf(sL[cq*4+3][r]);
  *(ushort4*)(wT + (size_t)(n0+r)*K + k0 + cq*4) = o;
}

// bout[n] = bias[n]  (init for split-K accumulation)
__global__ void copy_bias_kernel(const float* __restrict__ bias, float* __restrict__ bout, int Nn){
  int i = blockIdx.x*256 + threadIdx.x;
  if (i < Nn) bout[i] = bias[i];
}

// bout[n] += sum_{k in chunk} b_ln[k]*W[k,n]   grid (ceil(Nn/256), K/64)
__global__ __launch_bounds__(256) void fuse_b_acc(
    const float* __restrict__ bln, const float* __restrict__ w,
    float* __restrict__ bout, int K, int Nn)
{
  int n = blockIdx.x*256 + threadIdx.x;
  int k0 = blockIdx.y*64;
  if (n >= Nn) return;
  float acc = 0.f;
  #pragma unroll
  for (int k = 0; k < 64; ++k)
    acc = fmaf(bln[k0+k], w[(size_t)(k0+k)*Nn + n], acc);
  atomicAdd(&bout[n], acc);
}

__global__ void zero_kernel(float* __restrict__ p, long long total){
  long long i = (long long)blockIdx.x*256 + threadIdx.x;
  if (i < total) p[i] = 0.0f;
}

// ---------------- MFMA GEMM kernels ----------------
// Tile: BM=128, BN=64, BK=32. 4 waves; wave w: (wm=w>>1)*64 rows, (wn=w&1)*32 cols.
// Frags: A row=l&15 k=(l>>4)*8+j ; B col=l&15 ; D col=l&15 row=(l>>4)*4+i.

// C = silu(A @ WT^T + bias)
__global__ __launch_bounds__(256) void gemm_mfma_silu(
    const u16* __restrict__ A, int lda,
    const u16* __restrict__ BT, int ldbt, int wtc0,
    u16* __restrict__ C, int ldc,
    const float* __restrict__ bias, int K)
{
  __shared__ bf16x8 Al[4*129];
  __shared__ bf16x8 Bl[4*65];
  int t = threadIdx.x;
  int lane = t & 63, wid = t >> 6;
  int wm = wid >> 1, wn = wid & 1;
  int lrow = lane & 15, kcL = lane >> 4;
  int bm = blockIdx.y * 128, bn = blockIdx.x * 64;
  f32x4 acc[4][2] = {};
  for (int k0 = 0; k0 < K; k0 += 32) {
    #pragma unroll
    for (int i = 0; i < 2; ++i) {
      int u = t + i*256;
      int r = u >> 2, kc = u & 3;
      Al[kc*129 + r] = *(const bf16x8*)(A + (size_t)(bm + r)*lda + k0 + kc*8);
    }
    {
      int col = t >> 2, kc = t & 3;
      Bl[kc*65 + col] = *(const bf16x8*)(BT + (size_t)(wtc0 + bn + col)*ldbt + k0 + kc*8);
    }
    __syncthreads();
    bf16x8 af[4], bfr[2];
    #pragma unroll
    for (int mr = 0; mr < 4; ++mr) af[mr] = Al[kcL*129 + wm*64 + mr*16 + lrow];
    #pragma unroll
    for (int nr = 0; nr < 2; ++nr) bfr[nr] = Bl[kcL*65 + wn*32 + nr*16 + lrow];
    #pragma unroll
    for (int mr = 0; mr < 4; ++mr)
      #pragma unroll
      for (int nr = 0; nr < 2; ++nr)
        acc[mr][nr] = MFMA16(af[mr], bfr[nr], acc[mr][nr], 0, 0, 0);
    __syncthreads();
  }
  #pragma unroll
  for (int mr = 0; mr < 4; ++mr)
    #pragma unroll
    for (int nr = 0; nr < 2; ++nr) {
      int col = bn + wn*32 + nr*16 + lrow;
      float bs = bias[wtc0 + col];
      #pragma unroll
      for (int i = 0; i < 4; ++i) {
        int row = bm + wm*64 + mr*16 + kcL*4 + i;
        C[(size_t)row*ldc + col] = f2bf(siluf(acc[mr][nr][i] + bs));
      }
    }
}

// attn = relu(qq@kk^T/GS)^2 per group. grid (4, 2, G)
__global__ __launch_bounds__(256) void score_mfma(
    const u16* __restrict__ eqk, const float* __restrict__ osg,
    const float* __restrict__ osb, u16* __restrict__ attn)
{
  __shared__ bf16x8 Al[4*129];
  __shared__ bf16x8 Bl[4*65];
  int t = threadIdx.x;
  int lane = t & 63, wid = t >> 6;
  int wm = wid >> 1, wn = wid & 1;
  int lrow = lane & 15, kcL = lane >> 4;
  int g = blockIdx.z;
  int bm = blockIdx.y * 128, bn = blockIdx.x * 64;
  const u16* base = eqk + (size_t)g*GSZ*128;
  f32x4 acc[4][2] = {};
  for (int k0 = 0; k0 < 128; k0 += 32) {
    #pragma unroll
    for (int i = 0; i < 2; ++i) {
      int u = t + i*256;
      int r = u >> 2, kc = u & 3;
      bf16x8 raw = *(const bf16x8*)(base + (size_t)(bm + r)*128 + k0 + kc*8);
      bf16x8 v;
      #pragma unroll
      for (int j = 0; j < 8; ++j) {
        int kk = k0 + kc*8 + j;
        v[j] = (short)f2bf(fmaf(bf2f((u16)raw[j]), osg[kk], osb[kk]));   // quad_q row 0
      }
      Al[kc*129 + r] = v;
    }
    {
      int col = t >> 2, kc = t & 3;
      bf16x8 raw = *(const bf16x8*)(base + (size_t)(bn + col)*128 + k0 + kc*8);
      bf16x8 v;
      #pragma unroll
      for (int j = 0; j < 8; ++j) {
        int kk = k0 + kc*8 + j;
        v[j] = (short)f2bf(fmaf(bf2f((u16)raw[j]), osg[2*128+kk], osb[2*128+kk])); // quad_k row 2
      }
      Bl[kc*65 + col] = v;
    }
    __syncthreads();
    bf16x8 af[4], bfr[2];
    #pragma unroll
    for (int mr = 0; mr < 4; ++mr) af[mr] = Al[kcL*129 + wm*64 + mr*16 + lrow];
    #pragma unroll
    for (int nr = 0; nr < 2; ++nr) bfr[nr] = Bl[kcL*65 + wn*32 + nr*16 + lrow];
    #pragma unroll
    for (int mr = 0; mr < 4; ++mr)
      #pragma unroll
      for (int nr = 0; nr < 2; ++nr)
        acc[mr][nr] = MFMA16(af[mr], bfr[nr], acc[mr][nr], 0, 0, 0);
    __syncthreads();
  }
  #pragma unroll
  for (int mr = 0; mr < 4; ++mr)
    #pragma unroll
    for (int nr = 0; nr < 2; ++nr) {
      int col = bn + wn*32 + nr*16 + lrow;
      #pragma unroll
      for (int i = 0; i < 4; ++i) {
        int row = bm + wm*64 + mr*16 + kcL*4 + i;
        float s = fmaxf(acc[mr][nr][i] * (1.0f/GSZ), 0.0f);
        attn[((size_t)g*GSZ + row)*GSZ + col] = f2bf(s*s);
      }
    }
}

// F[d][e] += inv_n * sum_n (eqk[n,d]*g3+b3) * h[n,e].  grid (2048/64, 16)
__global__ __launch_bounds__(256) void linkv_mfma(
    const u16* __restrict__ eqk, const float* __restrict__ osg, const float* __restrict__ osb,
    const u16* __restrict__ h, float* __restrict__ F, float inv_n, int N)
{
  __shared__ bf16x8 Al[4*129];
  __shared__ bf16x8 Bl[4*65];
  int t = threadIdx.x;
  int lane = t & 63, wid = t >> 6;
  int wm = wid >> 1, wn = wid & 1;
  int lrow = lane & 15, kcL = lane >> 4;
  int e0 = blockIdx.x * 64;
  int Kslice = N / gridDim.y;
  int n0base = blockIdx.y * Kslice;
  f32x4 acc[4][2] = {};
  for (int k0 = 0; k0 < Kslice; k0 += 32) {
    int nb = n0base + k0;
    #pragma unroll
    for (int i = 0; i < 2; ++i) {
      int d = (t & 63) + i*64;
      int kc = t >> 6;
      float g3 = osg[3*128+d], b3 = osb[3*128+d];
      bf16x8 v;
      #pragma unroll
      for (int j = 0; j < 8; ++j)
        v[j] = (short)f2bf(fmaf(bf2f(eqk[(size_t)(nb + kc*8 + j)*128 + d]), g3, b3));
      Al[kc*129 + d] = v;
    }
    {
      int col = t & 63, kc = t >> 6;
      bf16x8 v;
      #pragma unroll
      for (int j = 0; j < 8; ++j)
        v[j] = (short)h[(size_t)(nb + kc*8 + j)*2048 + e0 + col];
      Bl[kc*65 + col] = v;
    }
    __syncthreads();
    bf16x8 af[4], bfr[2];
    #pragma unroll
    for (int mr = 0; mr < 4; ++mr) af[mr] = Al[kcL*129 + wm*64 + mr*16 + lrow];
    #pragma unroll
    for (int nr = 0; nr < 2; ++nr) bfr[nr] = Bl[kcL*65 + wn*32 + nr*16 + lrow];
    #pragma unroll
    for (int mr = 0; mr < 4; ++mr)
      #pragma unroll
      for (int nr = 0; nr < 2; ++nr)
        acc[mr][nr] = MFMA16(af[mr], bfr[nr], acc[mr][nr], 0, 0, 0);
    __syncthreads();
  }
  #pragma unroll
  for (int mr = 0; mr < 4; ++mr)
    #pragma unroll
    for (int nr = 0; nr < 2; ++nr) {
      int e = e0 + wn*32 + nr*16 + lrow;
      #pragma unroll
      for (int i = 0; i < 4; ++i) {
        int d = wm*64 + mr*16 + kcL*4 + i;
        atomicAdd(&F[(size_t)d*2048 + e], acc[mr][nr][i]*inv_n);
      }
    }
}

// FTg[e][d] = g1[d]*F[d][e] (bf16) ; cvec[e] = sum_d b1[d]*F[d][e]
__global__ __launch_bounds__(256) void fconv_kernel(
    const float* __restrict__ F, const float* __restrict__ osg, const float* __restrict__ osb,
    u16* __restrict__ FTg, float* __restrict__ cvec)
{
  __shared__ float g1s[128], b1s[128];
  int t = threadIdx.x;
  if (t < 128) { g1s[t] = osg[128+t]; b1s[t] = osb[128+t]; }
  __syncthreads();
  int e = blockIdx.x*256 + t;
  float c = 0.f;
  for (int d = 0; d < 128; ++d) {
    float f = F[(size_t)d*2048 + e];
    c = fmaf(b1s[d], f, c);
    FTg[(size_t)e*128 + d] = f2bf(g1s[d] * f);
  }
  cvec[e] = c;
}

// fused quad+lin attention + gate.  grid (1024/64, 2, G)
__global__ __launch_bounds__(256) void quadlin_mfma(
    const u16* __restrict__ attn, const u16* __restrict__ h,
    const u16* __restrict__ eqk, const u16* __restrict__ FTg,
    const float* __restrict__ cvec, u16* __restrict__ T2)
{
  __shared__ bf16x8 Al[4*129];
  __shared__ bf16x8 Bv[4*65];
  __shared__ bf16x8 Bu[4*65];
  int t = threadIdx.x;
  int lane = t & 63, wid = t >> 6;
  int wm = wid >> 1, wn = wid & 1;
  int lrow = lane & 15, kcL = lane >> 4;
  int g = blockIdx.z;
  int bm = blockIdx.y * 128, cb = blockIdx.x * 64;
  size_t rowbase = (size_t)g * GSZ;
  f32x4 accV[4][2] = {}, accU[4][2] = {};
  // phase 1: quad attention, K=256, B = h columns
  for (int k0 = 0; k0 < GSZ; k0 += 32) {
    #pragma unroll
    for (int i = 0; i < 2; ++i) {
      int u = t + i*256;
      int r = u >> 2, kc = u & 3;
      Al[kc*129 + r] = *(const bf16x8*)(attn + ((size_t)(rowbase + bm + r))*GSZ + k0 + kc*8);
    }
    {
      int col = t & 63, kc = t >> 6;
      bf16x8 vv, uu;
      #pragma unroll
      for (int j = 0; j < 8; ++j) {
        size_t hrow = (rowbase + k0 + kc*8 + j)*2048;
        vv[j] = (short)h[hrow + cb + col];
        uu[j] = (short)h[hrow + 1024 + cb + col];
      }
      Bv[kc*65 + col] = vv;
      Bu[kc*65 + col] = uu;
    }
    __syncthreads();
    bf16x8 af[4], bv[2], bu[2];
    #pragma unroll
    for (int mr = 0; mr < 4; ++mr) af[mr] = Al[kcL*129 + wm*64 + mr*16 + lrow];
    #pragma unroll
    for (int nr = 0; nr < 2; ++nr) { bv[nr] = Bv[kcL*65 + wn*32 + nr*16 + lrow];
                                     bu[nr] = Bu[kcL*65 + wn*32 + nr*16 + lrow]; }
    #pragma unroll
    for (int mr = 0; mr < 4; ++mr)
      #pragma unroll
      for (int nr = 0; nr < 2; ++nr) {
        accV[mr][nr] = MFMA16(af[mr], bv[nr], accV[mr][nr], 0, 0, 0);
        accU[mr][nr] = MFMA16(af[mr], bu[nr], accU[mr][nr], 0, 0, 0);
      }
    __syncthreads();
  }
  // phase 2: linear attention, K=128, A = raw eqk rows, B = FTg rows (g1 folded, b1 in cvec)
  for (int k0 = 0; k0 < 128; k0 += 32) {
    #pragma unroll
    for (int i = 0; i < 2; ++i) {
      int u = t + i*256;
      int r = u >> 2, kc = u & 3;
      Al[kc*129 + r] = *(const bf16x8*)(eqk + (rowbase + bm + r)*128 + k0 + kc*8);
    }
    {
      int col = t >> 2, kc = t & 3;
      Bv[kc*65 + col] = *(const bf16x8*)(FTg + (size_t)(cb + col)*128 + k0 + kc*8);
      Bu[kc*65 + col] = *(const bf16x8*)(FTg + (size_t)(1024 + cb + col)*128 + k0 + kc*8);
    }
    __syncthreads();
    bf16x8 af[4], bv[2], bu[2];
    #pragma unroll
    for (int mr = 0; mr < 4; ++mr) af[mr] = Al[kcL*129 + wm*64 + mr*16 + lrow];
    #pragma unroll
    for (int nr = 0; nr < 2; ++nr) { bv[nr] = Bv[kcL*65 + wn*32 + nr*16 + lrow];
                                     bu[nr] = Bu[kcL*65 + wn*32 + nr*16 + lrow]; }
    #pragma unroll
    for (int mr = 0; mr < 4; ++mr)
      #pragma unroll
      for (int nr = 0; nr < 2; ++nr) {
        accV[mr][nr] = MFMA16(af[mr], bv[nr], accV[mr][nr], 0, 0, 0);
        accU[mr][nr] = MFMA16(af[mr], bu[nr], accU[mr][nr], 0, 0, 0);
      }
    __syncthreads();
  }
  // epilogue: gate
  #pragma unroll
  for (int mr = 0; mr < 4; ++mr)
    #pragma unroll
    for (int nr = 0; nr < 2; ++nr) {
      int c = cb + wn*32 + nr*16 + lrow;
      float cV = cvec[c], cU = cvec[1024 + c];
      #pragma unroll
      for (int i = 0; i < 4; ++i) {
        size_t n = rowbase + bm + wm*64 + mr*16 + kcL*4 + i;
        float v = bf2f(h[n*2048 + c]);
        float u = bf2f(h[n*2048 + 1024 + c]);
        float av = accV[mr][nr][i] + cV;
        float au = accU[mr][nr][i] + cU;
        T2[n*1024 + c] = f2bf(au * v * sigm(av * u));
      }
    }
}

// ---------------- conv / norm kernels ----------------

__global__ __launch_bounds__(256) void dwconv_bf16(
    const u16* __restrict__ xin, int ldin, const float* __restrict__ kern,
    u16* __restrict__ y, int ldout, int N)
{
  __shared__ float tile[48][64];
  int c0 = blockIdx.x * 64;
  int n0 = blockIdx.y * 32;
  int t = threadIdx.x;
  int tx = t & 63, ty = t >> 6;
  #pragma unroll
  for (int it = 0; it < 12; ++it) {
    int idx = t + it*256;
    int r = idx >> 6, c = idx & 63;
    int gn = n0 - 8 + r;
    tile[r][c] = (gn >= 0 && gn < N) ? bf2f(xin[(long long)gn*ldin + c0 + c]) : 0.0f;
  }
  __syncthreads();
  int ch = c0 + tx;
  float kr[17];
  #pragma unroll
  for (int k = 0; k < 17; ++k) kr[k] = kern[ch*17 + k];
  #pragma unroll
  for (int rr = 0; rr < 8; ++rr) {
    int r = ty*8 + rr;
    float s = 0.0f;
    #pragma unroll
    for (int k = 0; k < 17; ++k) s = fmaf(kr[k], tile[r+k][tx], s);
    y[(long long)(n0 + r)*ldout + ch] = f2bf(tile[r+8][tx] + s);
  }
}

__global__ __launch_bounds__(256) void dwconv_final(
    const u16* __restrict__ xin, const float* __restrict__ kern,
    const float* __restrict__ resid, float* __restrict__ y, int N)
{
  __shared__ float tile[48][64];
  int c0 = blockIdx.x * 64;
  int n0 = blockIdx.y * 32;
  int t = threadIdx.x;
  int tx = t & 63, ty = t >> 6;
  #pragma unroll
  for (int it = 0; it < 12; ++it) {
    int idx = t + it*256;
    int r = idx >> 6, c = idx & 63;
    int gn = n0 - 8 + r;
    tile[r][c] = (gn >= 0 && gn < N) ? bf2f(xin[(long long)gn*512 + c0 + c]) : 0.0f;
  }
  __syncthreads();
  int ch = c0 + tx;
  float kr[17];
  #pragma unroll
  for (int k = 0; k < 17; ++k) kr[k] = kern[ch*17 + k];
  #pragma unroll
  for (int rr = 0; rr < 8; ++rr) {
    int r = ty*8 + rr;
    float s = 0.0f;
    #pragma unroll
    for (int k = 0; k < 17; ++k) s = fmaf(kr[k], tile[r+k][tx], s);
    long long gi = (long long)(n0 + r)*512 + ch;
    y[gi] = resid[gi] + tile[r+8][tx] + s;
  }
}

__global__ __launch_bounds__(256) void ln1024_kernel(u16* __restrict__ buf)
{
  long long n = blockIdx.x;
  ushort4* p = (ushort4*)(buf + n*1024) + threadIdx.x;
  ushort4 q = *p;
  float a = bf2f(q.x), b = bf2f(q.y), c = bf2f(q.z), d = bf2f(q.w);
  float s = a+b+c+d;
  float ss = fmaf(a,a, fmaf(b,b, fmaf(c,c, d*d)));
  float2 r = blockReduce2(s, ss);
  float mu = r.x * (1.0f/1024.0f);
  float var = r.y * (1.0f/1024.0f) - mu*mu;
  float rs = rsqrtf(var + 1e-5f);
  q.x = f2bf((a-mu)*rs); q.y = f2bf((b-mu)*rs);
  q.z = f2bf((c-mu)*rs); q.w = f2bf((d-mu)*rs);
  *p = q;
}

// ---------------- host launcher ----------------

extern "C" void kernel_launch(void* const* d_in, const int* in_sizes, int n_in,
                              void* d_out, int out_size, void* d_ws, size_t ws_size,
                              hipStream_t stream)
{
  const float* x        = (const float*)d_in[0];
  const float* th_ln_g  = (const float*)d_in[2];
  const float* th_ln_b  = (const float*)d_in[3];
  const float* th_w     = (const float*)d_in[4];
  const float* th_b     = (const float*)d_in[5];
  const float* th_conv  = (const float*)d_in[6];
  const float* qk_ln_g  = (const float*)d_in[7];
  const float* qk_ln_b  = (const float*)d_in[8];
  const float* qk_w     = (const float*)d_in[9];
  const float* qk_b     = (const float*)d_in[10];
  const float* qk_conv  = (const float*)d_in[11];
  const float* osg      = (const float*)d_in[12];
  const float* osb      = (const float*)d_in[13];
  const float* out_ln_g = (const float*)d_in[14];
  const float* out_ln_b = (const float*)d_in[15];
  const float* out_w    = (const float*)d_in[16];
  const float* out_b    = (const float*)d_in[17];
  const float* out_conv = (const float*)d_in[18];

  const int N = in_sizes[0] / 512;          // 16384
  const float inv_n = 1.0f / (float)N;
  const int G = N / GSZ;                    // 64
  char* wsb = (char*)d_ws;

  // ---- workspace layout (bytes), lifetime-aliased ----
  size_t o_h    = 0;                                    // h bf16: N*2048
  size_t o_T2   = o_h   + (size_t)N*2048*2;             // T2 bf16: N*1024 (nx aliases)
  size_t o_sc   = o_T2  + (size_t)N*1024*2;             // scratch bf16: N*512
  size_t o_eqk  = o_sc  + (size_t)N*512*2;              // Eqk bf16: N*128
  size_t o_dqk  = o_eqk + (size_t)N*128*2;              // Dqk bf16 N*128 (aliases F/FTg/cvec)
  size_t dq_sz  = (size_t)N*128*2;                      // 4 MB
  size_t o_wth  = o_dqk + dq_sz;
  size_t o_wqk  = o_wth + (size_t)2048*512*2;           // WthT
  size_t o_wout = o_wqk + (size_t)128*512*2;            // WqkT
  size_t o_bth  = o_wout+ (size_t)512*1024*2;           // WoutT
  size_t o_bqk  = o_bth + 2048*4;
  size_t o_bout = o_bqk + 128*4;
  size_t required = o_bout + 512*4;
  if (ws_size < required) return;

  u16*   h    = (u16*)(wsb + o_h);
  u16*   T2   = (u16*)(wsb + o_T2);
  u16*   nx   = T2;                       // alias: nx dead before T2 written
  u16*   scC  = (u16*)(wsb + o_sc);
  u16*   Eqk  = (u16*)(wsb + o_eqk);
  u16*   Dqk  = (u16*)(wsb + o_dqk);
  float* F    = (float*)(wsb + o_dqk);                     // 128*2048*4 = 1 MB
  u16*   FTg  = (u16*)(wsb + o_dqk + (size_t)128*2048*4);  // 0.5 MB
  float* cvec = (float*)(wsb + o_dqk + (size_t)128*2048*4 + (size_t)2048*128*2);
  u16*   WthT = (u16*)(wsb + o_wth);
  u16*   WqkT = (u16*)(wsb + o_wqk);
  u16*   WoutT= (u16*)(wsb + o_wout);
  float* Bth  = (float*)(wsb + o_bth);
  float* Bqk  = (float*)(wsb + o_bqk);
  float* Bout = (float*)(wsb + o_bout);

  // ---- weight prep ----
  hipLaunchKernelGGL(fuse_wT_kernel, dim3(16, 64), dim3(256), 0, stream, th_ln_g, th_w, WthT, 512, 2048);
  hipLaunchKernelGGL(fuse_wT_kernel, dim3(16, 4),  dim3(256), 0, stream, qk_ln_g, qk_w, WqkT, 512, 128);
  hipLaunchKernelGGL(fuse_wT_kernel, dim3(32, 16), dim3(256), 0, stream, out_ln_g, out_w, WoutT, 1024, 512);
  // bias fusion: bout = bias; bout += b_ln @ W   (split-K atomics, parallel)
  hipLaunchKernelGGL(copy_bias_kernel, dim3(8), dim3(256), 0, stream, th_b, Bth, 2048);
  hipLaunchKernelGGL(copy_bias_kernel, dim3(1), dim3(256), 0, stream, qk_b, Bqk, 128);
  hipLaunchKernelGGL(copy_bias_kernel, dim3(2), dim3(256), 0, stream, out_b, Bout, 512);
  hipLaunchKernelGGL(fuse_b_acc, dim3(8, 8),  dim3(256), 0, stream, th_ln_b,  th_w,  Bth, 512, 2048);
  hipLaunchKernelGGL(fuse_b_acc, dim3(1, 8),  dim3(256), 0, stream, qk_ln_b,  qk_w,  Bqk, 512, 128);
  hipLaunchKernelGGL(fuse_b_acc, dim3(2, 16), dim3(256), 0, stream, out_ln_b, out_w, Bout, 1024, 512);

  // ---- token shift + LN core ----
  hipLaunchKernelGGL(shift_ln_kernel, dim3(N), dim3(256), 0, stream, x, nx, N);

  // ---- th branch, 4 column chunks of 512 ----
  for (int ch = 0; ch < 4; ++ch) {
    hipLaunchKernelGGL(gemm_mfma_silu, dim3(8, N/128), dim3(256), 0, stream,
                       nx, 512, WthT, 512, ch*512, scC, 512, Bth, 512);
    hipLaunchKernelGGL(dwconv_bf16, dim3(8, N/32), dim3(256), 0, stream,
                       scC, 512, th_conv + (size_t)ch*512*17, h + (size_t)ch*512, 2048, N);
  }

  // ---- qk branch ----
  hipLaunchKernelGGL(gemm_mfma_silu, dim3(2, N/128), dim3(256), 0, stream,
                     nx, 512, WqkT, 512, 0, Dqk, 128, Bqk, 512);
  hipLaunchKernelGGL(dwconv_bf16, dim3(2, N/32), dim3(256), 0, stream,
                     Dqk, 128, qk_conv, Eqk, 128, N);

  // ---- linear attention kv summary ----
  hipLaunchKernelGGL(zero_kernel, dim3(1024), dim3(256), 0, stream, F, (long long)128*2048);
  hipLaunchKernelGGL(linkv_mfma, dim3(32, 16), dim3(256), 0, stream, Eqk, osg, osb, h, F, inv_n, N);
  hipLaunchKernelGGL(fconv_kernel, dim3(8), dim3(256), 0, stream, F, osg, osb, FTg, cvec);

  // ---- quadratic attention scores -> scC ----
  hipLaunchKernelGGL(score_mfma, dim3(4, 2, G), dim3(256), 0, stream, Eqk, osg, osb, scC);

  // ---- fused quad + lin + gate -> T2 ----
  hipLaunchKernelGGL(quadlin_mfma, dim3(16, 2, G), dim3(256), 0, stream,
                     scC, h, Eqk, FTg, cvec, T2);

  // ---- out branch ----
  hipLaunchKernelGGL(ln1024_kernel, dim3(N), dim3(256), 0, stream, T2);
  hipLaunchKernelGGL(gemm_mfma_silu, dim3(8, N/128), dim3(256), 0, stream,
                     T2, 1024, WoutT, 1024, 0, scC, 512, Bout, 1024);
  hipLaunchKernelGGL(dwconv_final, dim3(8, N/32), dim3(256), 0, stream,
                     scC, out_conv, x, (float*)d_out, N);
}

// Round 5
// 448.224 us; speedup vs baseline: 4.6788x; 1.0673x over previous
//
#include <hip/hip_runtime.h>
#include <math.h>

#define GSZ 256

typedef unsigned short u16;
typedef short bf16x8 __attribute__((ext_vector_type(8)));
typedef float f32x4 __attribute__((ext_vector_type(4)));
#define MFMA16 __builtin_amdgcn_mfma_f32_16x16x32_bf16

__device__ __forceinline__ float bf2f(u16 u){
  union { unsigned int i; float f; } x; x.i = ((unsigned int)u) << 16; return x.f;
}
__device__ __forceinline__ u16 f2bf(float f){
  union { float ff; unsigned int i; } x; x.ff = f;
  unsigned int r = x.i + 0x7fffu + ((x.i >> 16) & 1u);
  return (u16)(r >> 16);
}
__device__ __forceinline__ float sigm(float x){ return 1.0f/(1.0f+__expf(-x)); }
__device__ __forceinline__ float siluf(float x){ return x/(1.0f+__expf(-x)); }

// async global->LDS, 16B per lane; LDS dest = uniform base + lane*16
__device__ __forceinline__ void gload16(const void* g, void* l){
  __builtin_amdgcn_global_load_lds(
      (const __attribute__((address_space(1))) void*)g,
      (__attribute__((address_space(3))) void*)l, 16, 0, 0);
}

__device__ __forceinline__ float2 blockReduce2(float s, float ss){
  __shared__ float red[8];
  #pragma unroll
  for (int off=32; off>0; off>>=1){
    s  += __shfl_down(s, off, 64);
    ss += __shfl_down(ss, off, 64);
  }
  int lane = threadIdx.x & 63, wid = threadIdx.x >> 6;
  if (lane==0){ red[wid]=s; red[4+wid]=ss; }
  __syncthreads();
  float2 r;
  r.x = red[0]+red[1]+red[2]+red[3];
  r.y = red[4]+red[5]+red[6]+red[7];
  return r;
}

// ---------------- small prep kernels ----------------

__global__ __launch_bounds__(256) void shift_ln_kernel(
    const float* __restrict__ x, u16* __restrict__ out, int N)
{
  int n = blockIdx.x;
  int t = threadIdx.x;
  float v0 = (n > 0) ? x[(long long)(n-1)*512 + t] : 0.0f;
  float v1 = x[(long long)n*512 + 256 + t];
  float2 r = blockReduce2(v0+v1, fmaf(v0,v0,v1*v1));
  float mu = r.x * (1.0f/512.0f);
  float var = r.y * (1.0f/512.0f) - mu*mu;
  float rs = rsqrtf(var + 1e-5f);
  long long base = (long long)n*512;
  out[base + t]       = f2bf((v0-mu)*rs);
  out[base + 256 + t] = f2bf((v1-mu)*rs);
}

// WT[n][k] = g[k]*W[k][n] -> bf16.  grid (K/32, Nn/32), 256 thr
__global__ __launch_bounds__(256) void fuse_wT_kernel(
    const float* __restrict__ g, const float* __restrict__ w,
    u16* __restrict__ wT, int K, int Nn)
{
  __shared__ float sL[32][33];
  int k0 = blockIdx.x*32, n0 = blockIdx.y*32;
  int t = threadIdx.x;
  int r = t >> 3, cq = t & 7;
  float4 v = *(const float4*)(w + (size_t)(k0+r)*Nn + n0 + cq*4);
  float gg = g[k0+r];
  sL[r][cq*4+0] = v.x*gg; sL[r][cq*4+1] = v.y*gg;
  sL[r][cq*4+2] = v.z*gg; sL[r][cq*4+3] = v.w*gg;
  __syncthreads();
  ushort4 o;
  o.x = f2bf(sL[cq*4+0][r]); o.y = f2bf(sL[cq*4+1][r]);
  o.z = f2bf(sL[cq*4+2][r]); o.w = f2bf(sL[cq*4+3][r]);
  *(ushort4*)(wT + (size_t)(n0+r)*K + k0 + cq*4) = o;
}

// bout[n] = bias[n]
__global__ void copy_bias_kernel(const float* __restrict__ bias, float* __restrict__ bout, int Nn){
  int i = blockIdx.x*256 + threadIdx.x;
  if (i < Nn) bout[i] = bias[i];
}

// bout[n] += sum_{k chunk} b_ln[k]*W[k,n]   grid (ceil(Nn/256), K/64)
__global__ __launch_bounds__(256) void fuse_b_acc(
    const float* __restrict__ bln, const float* __restrict__ w,
    float* __restrict__ bout, int K, int Nn)
{
  int n = blockIdx.x*256 + threadIdx.x;
  int k0 = blockIdx.y*64;
  if (n >= Nn) return;
  float acc = 0.f;
  #pragma unroll
  for (int k = 0; k < 64; ++k)
    acc = fmaf(bln[k0+k], w[(size_t)(k0+k)*Nn + n], acc);
  atomicAdd(&bout[n], acc);
}

__global__ void zero_kernel(float* __restrict__ p, long long total){
  long long i = (long long)blockIdx.x*256 + threadIdx.x;
  if (i < total) p[i] = 0.0f;
}

// ---------------- MFMA GEMM kernels (chunk-linear LDS + global_load_lds) --------------
// Chunk = 64 units x 16B. Unit l of chunk c = fragment of lane l:
//   rows: r = c*16 + (l&15), k-slice kc = l>>4 (8 bf16).
// Frag read = ds_read_b128 of contiguous 1KB (conflict-free).
// MFMA frags: A row=l&15 k=(l>>4)*8+j ; B col=l&15 ; D col=l&15 row=(l>>4)*4+i.

// C = silu(A @ WT^T + bias).  BM=128, BN=128, BK=32. grid (cols/128, M/128)
__global__ __launch_bounds__(256) void gemm_mfma_silu(
    const u16* __restrict__ A, int lda,
    const u16* __restrict__ BT, int ldbt, int wtc0,
    u16* __restrict__ C, int ldc,
    const float* __restrict__ bias, int K)
{
  __shared__ u16 lds[16*512];    // A chunks 0..7, B chunks 8..15
  int t = threadIdx.x;
  int lane = t & 63, wid = t >> 6;
  int wm = wid >> 1, wn = wid & 1;
  int lrow = lane & 15, kcL = lane >> 4;
  int bm = blockIdx.y*128, bn = blockIdx.x*128;
  const u16* gA0 = A + (size_t)(bm + wid*16 + lrow)*lda + kcL*8;
  const u16* gA1 = A + (size_t)(bm + (wid+4)*16 + lrow)*lda + kcL*8;
  const u16* gB0 = BT + (size_t)(wtc0 + bn + wid*16 + lrow)*ldbt + kcL*8;
  const u16* gB1 = BT + (size_t)(wtc0 + bn + (wid+4)*16 + lrow)*ldbt + kcL*8;
  u16* lA0 = lds + (size_t)wid*512;
  u16* lA1 = lds + (size_t)(wid+4)*512;
  u16* lB0 = lds + (size_t)(8+wid)*512;
  u16* lB1 = lds + (size_t)(12+wid)*512;
  const bf16x8* L = (const bf16x8*)lds;
  f32x4 acc[4][4] = {};
  for (int k0 = 0; k0 < K; k0 += 32) {
    gload16(gA0 + k0, lA0);
    gload16(gA1 + k0, lA1);
    gload16(gB0 + k0, lB0);
    gload16(gB1 + k0, lB1);
    __syncthreads();
    bf16x8 af[4], bfr[4];
    #pragma unroll
    for (int mr = 0; mr < 4; ++mr) af[mr] = L[(wm*4+mr)*64 + lane];
    #pragma unroll
    for (int nr = 0; nr < 4; ++nr) bfr[nr] = L[(8 + wn*4+nr)*64 + lane];
    #pragma unroll
    for (int mr = 0; mr < 4; ++mr)
      #pragma unroll
      for (int nr = 0; nr < 4; ++nr)
        acc[mr][nr] = MFMA16(af[mr], bfr[nr], acc[mr][nr], 0, 0, 0);
    __syncthreads();
  }
  #pragma unroll
  for (int mr = 0; mr < 4; ++mr)
    #pragma unroll
    for (int nr = 0; nr < 4; ++nr) {
      int col = bn + wn*64 + nr*16 + lrow;
      float bs = bias[wtc0 + col];
      #pragma unroll
      for (int i = 0; i < 4; ++i) {
        int row = bm + wm*64 + mr*16 + kcL*4 + i;
        C[(size_t)row*ldc + col] = f2bf(siluf(acc[mr][nr][i] + bs));
      }
    }
}

// attn = relu(qq@kk^T/GS)^2 per group. BM=128, BN=64. grid (4, 2, G)
__global__ __launch_bounds__(256) void score_mfma(
    const u16* __restrict__ eqk, const float* __restrict__ osg,
    const float* __restrict__ osb, u16* __restrict__ attn)
{
  __shared__ u16 lds[12*512];    // A chunks 0..7, B chunks 8..11
  int t = threadIdx.x;
  int lane = t & 63, wid = t >> 6;
  int wm = wid >> 1, wn = wid & 1;
  int lrow = lane & 15, kcL = lane >> 4;
  int g = blockIdx.z;
  int bm = blockIdx.y * 128, bn = blockIdx.x * 64;
  const u16* base = eqk + (size_t)g*GSZ*128;
  const bf16x8* L = (const bf16x8*)lds;
  f32x4 acc[4][2] = {};
  for (int k0 = 0; k0 < 128; k0 += 32) {
    #pragma unroll
    for (int i = 0; i < 2; ++i) {          // A: quad_q = eqk*g0+b0, chunk-linear
      int u = t + i*256;
      int r = (u>>6)*16 + (u&15);
      int kc = (u>>4)&3;
      bf16x8 raw = *(const bf16x8*)(base + (size_t)(bm + r)*128 + k0 + kc*8);
      bf16x8 v;
      #pragma unroll
      for (int j = 0; j < 8; ++j) {
        int kk = k0 + kc*8 + j;
        v[j] = (short)f2bf(fmaf(bf2f((u16)raw[j]), osg[kk], osb[kk]));
      }
      *(bf16x8*)(lds + (size_t)u*8) = v;
    }
    {                                       // B: quad_k = eqk*g2+b2
      int r = (t>>6)*16 + (t&15);
      int kc = (t>>4)&3;
      bf16x8 raw = *(const bf16x8*)(base + (size_t)(bn + r)*128 + k0 + kc*8);
      bf16x8 v;
      #pragma unroll
      for (int j = 0; j < 8; ++j) {
        int kk = k0 + kc*8 + j;
        v[j] = (short)f2bf(fmaf(bf2f((u16)raw[j]), osg[2*128+kk], osb[2*128+kk]));
      }
      *(bf16x8*)(lds + (size_t)(8*512) + (size_t)t*8) = v;
    }
    __syncthreads();
    bf16x8 af[4], bfr[2];
    #pragma unroll
    for (int mr = 0; mr < 4; ++mr) af[mr] = L[(wm*4+mr)*64 + lane];
    #pragma unroll
    for (int nr = 0; nr < 2; ++nr) bfr[nr] = L[(8 + wn*2+nr)*64 + lane];
    #pragma unroll
    for (int mr = 0; mr < 4; ++mr)
      #pragma unroll
      for (int nr = 0; nr < 2; ++nr)
        acc[mr][nr] = MFMA16(af[mr], bfr[nr], acc[mr][nr], 0, 0, 0);
    __syncthreads();
  }
  #pragma unroll
  for (int mr = 0; mr < 4; ++mr)
    #pragma unroll
    for (int nr = 0; nr < 2; ++nr) {
      int col = bn + wn*32 + nr*16 + lrow;
      #pragma unroll
      for (int i = 0; i < 4; ++i) {
        int row = bm + wm*64 + mr*16 + kcL*4 + i;
        float s = fmaxf(acc[mr][nr][i] * (1.0f/GSZ), 0.0f);
        attn[((size_t)g*GSZ + row)*GSZ + col] = f2bf(s*s);
      }
    }
}

// F[d][e] += inv_n * sum_n (eqk[n,d]*g3+b3) * h[n,e].  grid (2048/64, 16)
__global__ __launch_bounds__(256) void linkv_mfma(
    const u16* __restrict__ eqk, const float* __restrict__ osg, const float* __restrict__ osb,
    const u16* __restrict__ h, float* __restrict__ F, float inv_n, int N)
{
  __shared__ bf16x8 Al[4*129];
  __shared__ bf16x8 Bl[4*65];
  int t = threadIdx.x;
  int lane = t & 63, wid = t >> 6;
  int wm = wid >> 1, wn = wid & 1;
  int lrow = lane & 15, kcL = lane >> 4;
  int e0 = blockIdx.x * 64;
  int Kslice = N / gridDim.y;
  int n0base = blockIdx.y * Kslice;
  f32x4 acc[4][2] = {};
  for (int k0 = 0; k0 < Kslice; k0 += 32) {
    int nb = n0base + k0;
    #pragma unroll
    for (int i = 0; i < 2; ++i) {
      int d = (t & 63) + i*64;
      int kc = t >> 6;
      float g3 = osg[3*128+d], b3 = osb[3*128+d];
      bf16x8 v;
      #pragma unroll
      for (int j = 0; j < 8; ++j)
        v[j] = (short)f2bf(fmaf(bf2f(eqk[(size_t)(nb + kc*8 + j)*128 + d]), g3, b3));
      Al[kc*129 + d] = v;
    }
    {
      int col = t & 63, kc = t >> 6;
      bf16x8 v;
      #pragma unroll
      for (int j = 0; j < 8; ++j)
        v[j] = (short)h[(size_t)(nb + kc*8 + j)*2048 + e0 + col];
      Bl[kc*65 + col] = v;
    }
    __syncthreads();
    bf16x8 af[4], bfr[2];
    #pragma unroll
    for (int mr = 0; mr < 4; ++mr) af[mr] = Al[kcL*129 + wm*64 + mr*16 + lrow];
    #pragma unroll
    for (int nr = 0; nr < 2; ++nr) bfr[nr] = Bl[kcL*65 + wn*32 + nr*16 + lrow];
    #pragma unroll
    for (int mr = 0; mr < 4; ++mr)
      #pragma unroll
      for (int nr = 0; nr < 2; ++nr)
        acc[mr][nr] = MFMA16(af[mr], bfr[nr], acc[mr][nr], 0, 0, 0);
    __syncthreads();
  }
  #pragma unroll
  for (int mr = 0; mr < 4; ++mr)
    #pragma unroll
    for (int nr = 0; nr < 2; ++nr) {
      int e = e0 + wn*32 + nr*16 + lrow;
      #pragma unroll
      for (int i = 0; i < 4; ++i) {
        int d = wm*64 + mr*16 + kcL*4 + i;
        atomicAdd(&F[(size_t)d*2048 + e], acc[mr][nr][i]*inv_n);
      }
    }
}

// FTg[e][d] = g1[d]*F[d][e] (bf16) ; cvec[e] = sum_d b1[d]*F[d][e]
__global__ __launch_bounds__(256) void fconv_kernel(
    const float* __restrict__ F, const float* __restrict__ osg, const float* __restrict__ osb,
    u16* __restrict__ FTg, float* __restrict__ cvec)
{
  __shared__ float g1s[128], b1s[128];
  int t = threadIdx.x;
  if (t < 128) { g1s[t] = osg[128+t]; b1s[t] = osb[128+t]; }
  __syncthreads();
  int e = blockIdx.x*256 + t;
  float c = 0.f;
  for (int d = 0; d < 128; ++d) {
    float f = F[(size_t)d*2048 + e];
    c = fmaf(b1s[d], f, c);
    FTg[(size_t)e*128 + d] = f2bf(g1s[d] * f);
  }
  cvec[e] = c;
}

// fused quad+lin attention + gate.  BM=128, cols=64 (V and U). grid (1024/64, 2, G)
__global__ __launch_bounds__(256) void quadlin_mfma(
    const u16* __restrict__ attn, const u16* __restrict__ h,
    const u16* __restrict__ eqk, const u16* __restrict__ FTg,
    const float* __restrict__ cvec, u16* __restrict__ T2)
{
  __shared__ u16 lds[16*512];   // A chunks 0..7, BV 8..11, BU 12..15
  int t = threadIdx.x;
  int lane = t & 63, wid = t >> 6;
  int wm = wid >> 1, wn = wid & 1;
  int lrow = lane & 15, kcL = lane >> 4;
  int g = blockIdx.z;
  int bm = blockIdx.y * 128, cb = blockIdx.x * 64;
  size_t rowbase = (size_t)g * GSZ;
  const bf16x8* L = (const bf16x8*)lds;
  u16* lA0 = lds + (size_t)wid*512;
  u16* lA1 = lds + (size_t)(wid+4)*512;
  f32x4 accV[4][2] = {}, accU[4][2] = {};
  // ---- phase 1: quad attention, K=256. A=attn rows (gload), B=h columns (gather)
  const u16* gA0 = attn + (rowbase + bm + wid*16 + lrow)*GSZ + kcL*8;
  const u16* gA1 = attn + (rowbase + bm + (wid+4)*16 + lrow)*GSZ + kcL*8;
  int gcol = cb + ((t>>6)<<4) + (t&15);   // column this thread gathers
  int gkc  = (t&63)>>4;                   // k-slice
  for (int k0 = 0; k0 < GSZ; k0 += 32) {
    gload16(gA0 + k0, lA0);
    gload16(gA1 + k0, lA1);
    bf16x8 vv, uu;
    #pragma unroll
    for (int j = 0; j < 8; ++j) {
      size_t hrow = (rowbase + k0 + gkc*8 + j)*2048;
      vv[j] = (short)h[hrow + gcol];
      uu[j] = (short)h[hrow + 1024 + gcol];
    }
    *(bf16x8*)(lds + (size_t)(8*512) + (size_t)t*8)  = vv;
    *(bf16x8*)(lds + (size_t)(12*512) + (size_t)t*8) = uu;
    __syncthreads();
    bf16x8 af[4], bv[2], bu[2];
    #pragma unroll
    for (int mr = 0; mr < 4; ++mr) af[mr] = L[(wm*4+mr)*64 + lane];
    #pragma unroll
    for (int nr = 0; nr < 2; ++nr) { bv[nr] = L[(8 + wn*2+nr)*64 + lane];
                                     bu[nr] = L[(12 + wn*2+nr)*64 + lane]; }
    #pragma unroll
    for (int mr = 0; mr < 4; ++mr)
      #pragma unroll
      for (int nr = 0; nr < 2; ++nr) {
        accV[mr][nr] = MFMA16(af[mr], bv[nr], accV[mr][nr], 0, 0, 0);
        accU[mr][nr] = MFMA16(af[mr], bu[nr], accU[mr][nr], 0, 0, 0);
      }
    __syncthreads();
  }
  // ---- phase 2: linear attention, K=128. A=eqk rows, B=FTg rows (all gload)
  const u16* gA0b = eqk + (rowbase + bm + wid*16 + lrow)*128 + kcL*8;
  const u16* gA1b = eqk + (rowbase + bm + (wid+4)*16 + lrow)*128 + kcL*8;
  const u16* gBV  = FTg + (size_t)(cb + wid*16 + lrow)*128 + kcL*8;
  const u16* gBU  = FTg + (size_t)(1024 + cb + wid*16 + lrow)*128 + kcL*8;
  u16* lBV = lds + (size_t)(8+wid)*512;
  u16* lBU = lds + (size_t)(12+wid)*512;
  for (int k0 = 0; k0 < 128; k0 += 32) {
    gload16(gA0b + k0, lA0);
    gload16(gA1b + k0, lA1);
    gload16(gBV + k0, lBV);
    gload16(gBU + k0, lBU);
    __syncthreads();
    bf16x8 af[4], bv[2], bu[2];
    #pragma unroll
    for (int mr = 0; mr < 4; ++mr) af[mr] = L[(wm*4+mr)*64 + lane];
    #pragma unroll
    for (int nr = 0; nr < 2; ++nr) { bv[nr] = L[(8 + wn*2+nr)*64 + lane];
                                     bu[nr] = L[(12 + wn*2+nr)*64 + lane]; }
    #pragma unroll
    for (int mr = 0; mr < 4; ++mr)
      #pragma unroll
      for (int nr = 0; nr < 2; ++nr) {
        accV[mr][nr] = MFMA16(af[mr], bv[nr], accV[mr][nr], 0, 0, 0);
        accU[mr][nr] = MFMA16(af[mr], bu[nr], accU[mr][nr], 0, 0, 0);
      }
    __syncthreads();
  }
  // ---- epilogue: gate
  #pragma unroll
  for (int mr = 0; mr < 4; ++mr)
    #pragma unroll
    for (int nr = 0; nr < 2; ++nr) {
      int c = cb + wn*32 + nr*16 + lrow;
      float cV = cvec[c], cU = cvec[1024 + c];
      #pragma unroll
      for (int i = 0; i < 4; ++i) {
        size_t n = rowbase + bm + wm*64 + mr*16 + kcL*4 + i;
        float v = bf2f(h[n*2048 + c]);
        float u = bf2f(h[n*2048 + 1024 + c]);
        float av = accV[mr][nr][i] + cV;
        float au = accU[mr][nr][i] + cU;
        T2[n*1024 + c] = f2bf(au * v * sigm(av * u));
      }
    }
}

// ---------------- conv / norm kernels ----------------

__global__ __launch_bounds__(256) void dwconv_bf16(
    const u16* __restrict__ xin, int ldin, const float* __restrict__ kern,
    u16* __restrict__ y, int ldout, int N)
{
  __shared__ float tile[48][64];
  int c0 = blockIdx.x * 64;
  int n0 = blockIdx.y * 32;
  int t = threadIdx.x;
  int tx = t & 63, ty = t >> 6;
  #pragma unroll
  for (int it = 0; it < 3; ++it) {
    int idx = t + it*256;
    int r = idx >> 4, cq = (idx & 15)*4;
    int gn = n0 - 8 + r;
    float4 f;
    if (gn >= 0 && gn < N) {
      ushort4 q = *(const ushort4*)(xin + (size_t)gn*ldin + c0 + cq);
      f.x = bf2f(q.x); f.y = bf2f(q.y); f.z = bf2f(q.z); f.w = bf2f(q.w);
    } else { f.x = 0.f; f.y = 0.f; f.z = 0.f; f.w = 0.f; }
    *(float4*)&tile[r][cq] = f;
  }
  __syncthreads();
  int ch = c0 + tx;
  float kr[17];
  #pragma unroll
  for (int k = 0; k < 17; ++k) kr[k] = kern[ch*17 + k];
  #pragma unroll
  for (int rr = 0; rr < 8; ++rr) {
    int r = ty*8 + rr;
    float s = 0.0f;
    #pragma unroll
    for (int k = 0; k < 17; ++k) s = fmaf(kr[k], tile[r+k][tx], s);
    y[(size_t)(n0 + r)*ldout + ch] = f2bf(tile[r+8][tx] + s);
  }
}

__global__ __launch_bounds__(256) void dwconv_final(
    const u16* __restrict__ xin, const float* __restrict__ kern,
    const float* __restrict__ resid, float* __restrict__ y, int N)
{
  __shared__ float tile[48][64];
  int c0 = blockIdx.x * 64;
  int n0 = blockIdx.y * 32;
  int t = threadIdx.x;
  int tx = t & 63, ty = t >> 6;
  #pragma unroll
  for (int it = 0; it < 3; ++it) {
    int idx = t + it*256;
    int r = idx >> 4, cq = (idx & 15)*4;
    int gn = n0 - 8 + r;
    float4 f;
    if (gn >= 0 && gn < N) {
      ushort4 q = *(const ushort4*)(xin + (size_t)gn*512 + c0 + cq);
      f.x = bf2f(q.x); f.y = bf2f(q.y); f.z = bf2f(q.z); f.w = bf2f(q.w);
    } else { f.x = 0.f; f.y = 0.f; f.z = 0.f; f.w = 0.f; }
    *(float4*)&tile[r][cq] = f;
  }
  __syncthreads();
  int ch = c0 + tx;
  float kr[17];
  #pragma unroll
  for (int k = 0; k < 17; ++k) kr[k] = kern[ch*17 + k];
  #pragma unroll
  for (int rr = 0; rr < 8; ++rr) {
    int r = ty*8 + rr;
    float s = 0.0f;
    #pragma unroll
    for (int k = 0; k < 17; ++k) s = fmaf(kr[k], tile[r+k][tx], s);
    size_t gi = (size_t)(n0 + r)*512 + ch;
    y[gi] = resid[gi] + tile[r+8][tx] + s;
  }
}

__global__ __launch_bounds__(256) void ln1024_kernel(u16* __restrict__ buf)
{
  long long n = blockIdx.x;
  ushort4* p = (ushort4*)(buf + n*1024) + threadIdx.x;
  ushort4 q = *p;
  float a = bf2f(q.x), b = bf2f(q.y), c = bf2f(q.z), d = bf2f(q.w);
  float s = a+b+c+d;
  float ss = fmaf(a,a, fmaf(b,b, fmaf(c,c, d*d)));
  float2 r = blockReduce2(s, ss);
  float mu = r.x * (1.0f/1024.0f);
  float var = r.y * (1.0f/1024.0f) - mu*mu;
  float rs = rsqrtf(var + 1e-5f);
  q.x = f2bf((a-mu)*rs); q.y = f2bf((b-mu)*rs);
  q.z = f2bf((c-mu)*rs); q.w = f2bf((d-mu)*rs);
  *p = q;
}

// ---------------- host launcher ----------------

extern "C" void kernel_launch(void* const* d_in, const int* in_sizes, int n_in,
                              void* d_out, int out_size, void* d_ws, size_t ws_size,
                              hipStream_t stream)
{
  const float* x        = (const float*)d_in[0];
  const float* th_ln_g  = (const float*)d_in[2];
  const float* th_ln_b  = (const float*)d_in[3];
  const float* th_w     = (const float*)d_in[4];
  const float* th_b     = (const float*)d_in[5];
  const float* th_conv  = (const float*)d_in[6];
  const float* qk_ln_g  = (const float*)d_in[7];
  const float* qk_ln_b  = (const float*)d_in[8];
  const float* qk_w     = (const float*)d_in[9];
  const float* qk_b     = (const float*)d_in[10];
  const float* qk_conv  = (const float*)d_in[11];
  const float* osg      = (const float*)d_in[12];
  const float* osb      = (const float*)d_in[13];
  const float* out_ln_g = (const float*)d_in[14];
  const float* out_ln_b = (const float*)d_in[15];
  const float* out_w    = (const float*)d_in[16];
  const float* out_b    = (const float*)d_in[17];
  const float* out_conv = (const float*)d_in[18];

  const int N = in_sizes[0] / 512;          // 16384
  const float inv_n = 1.0f / (float)N;
  const int G = N / GSZ;                    // 64
  char* wsb = (char*)d_ws;

  // ---- workspace layout (bytes), lifetime-aliased ----
  size_t o_h    = 0;                                    // h bf16: N*2048
  size_t o_T2   = o_h   + (size_t)N*2048*2;             // T2 bf16: N*1024 (nx aliases)
  size_t o_sc   = o_T2  + (size_t)N*1024*2;             // scratch bf16: N*512
  size_t o_eqk  = o_sc  + (size_t)N*512*2;              // Eqk bf16: N*128
  size_t o_dqk  = o_eqk + (size_t)N*128*2;              // Dqk bf16 N*128 (aliases F/FTg/cvec)
  size_t dq_sz  = (size_t)N*128*2;                      // 4 MB
  size_t o_wth  = o_dqk + dq_sz;
  size_t o_wqk  = o_wth + (size_t)2048*512*2;           // WthT
  size_t o_wout = o_wqk + (size_t)128*512*2;            // WqkT
  size_t o_bth  = o_wout+ (size_t)1024*512*2;           // WoutT
  size_t o_bqk  = o_bth + 2048*4;
  size_t o_bout = o_bqk + 128*4;
  size_t required = o_bout + 512*4;
  if (ws_size < required) return;

  u16*   h    = (u16*)(wsb + o_h);
  u16*   T2   = (u16*)(wsb + o_T2);
  u16*   nx   = T2;                       // alias: nx dead before T2 written
  u16*   scC  = (u16*)(wsb + o_sc);
  u16*   Eqk  = (u16*)(wsb + o_eqk);
  u16*   Dqk  = (u16*)(wsb + o_dqk);
  float* F    = (float*)(wsb + o_dqk);                     // 1 MB
  u16*   FTg  = (u16*)(wsb + o_dqk + (size_t)128*2048*4);  // 0.5 MB
  float* cvec = (float*)(wsb + o_dqk + (size_t)128*2048*4 + (size_t)2048*128*2);
  u16*   WthT = (u16*)(wsb + o_wth);
  u16*   WqkT = (u16*)(wsb + o_wqk);
  u16*   WoutT= (u16*)(wsb + o_wout);
  float* Bth  = (float*)(wsb + o_bth);
  float* Bqk  = (float*)(wsb + o_bqk);
  float* Bout = (float*)(wsb + o_bout);

  // ---- weight prep ----
  hipLaunchKernelGGL(fuse_wT_kernel, dim3(16, 64), dim3(256), 0, stream, th_ln_g, th_w, WthT, 512, 2048);
  hipLaunchKernelGGL(fuse_wT_kernel, dim3(16, 4),  dim3(256), 0, stream, qk_ln_g, qk_w, WqkT, 512, 128);
  hipLaunchKernelGGL(fuse_wT_kernel, dim3(32, 16), dim3(256), 0, stream, out_ln_g, out_w, WoutT, 1024, 512);
  hipLaunchKernelGGL(copy_bias_kernel, dim3(8), dim3(256), 0, stream, th_b, Bth, 2048);
  hipLaunchKernelGGL(copy_bias_kernel, dim3(1), dim3(256), 0, stream, qk_b, Bqk, 128);
  hipLaunchKernelGGL(copy_bias_kernel, dim3(2), dim3(256), 0, stream, out_b, Bout, 512);
  hipLaunchKernelGGL(fuse_b_acc, dim3(8, 8),  dim3(256), 0, stream, th_ln_b,  th_w,  Bth, 512, 2048);
  hipLaunchKernelGGL(fuse_b_acc, dim3(1, 8),  dim3(256), 0, stream, qk_ln_b,  qk_w,  Bqk, 512, 128);
  hipLaunchKernelGGL(fuse_b_acc, dim3(2, 16), dim3(256), 0, stream, out_ln_b, out_w, Bout, 1024, 512);

  // ---- token shift + LN core ----
  hipLaunchKernelGGL(shift_ln_kernel, dim3(N), dim3(256), 0, stream, x, nx, N);

  // ---- th branch, 4 column chunks of 512 ----
  for (int ch = 0; ch < 4; ++ch) {
    hipLaunchKernelGGL(gemm_mfma_silu, dim3(4, N/128), dim3(256), 0, stream,
                       nx, 512, WthT, 512, ch*512, scC, 512, Bth, 512);
    hipLaunchKernelGGL(dwconv_bf16, dim3(8, N/32), dim3(256), 0, stream,
                       scC, 512, th_conv + (size_t)ch*512*17, h + (size_t)ch*512, 2048, N);
  }

  // ---- qk branch ----
  hipLaunchKernelGGL(gemm_mfma_silu, dim3(1, N/128), dim3(256), 0, stream,
                     nx, 512, WqkT, 512, 0, Dqk, 128, Bqk, 512);
  hipLaunchKernelGGL(dwconv_bf16, dim3(2, N/32), dim3(256), 0, stream,
                     Dqk, 128, qk_conv, Eqk, 128, N);

  // ---- linear attention kv summary ----
  hipLaunchKernelGGL(zero_kernel, dim3(1024), dim3(256), 0, stream, F, (long long)128*2048);
  hipLaunchKernelGGL(linkv_mfma, dim3(32, 16), dim3(256), 0, stream, Eqk, osg, osb, h, F, inv_n, N);
  hipLaunchKernelGGL(fconv_kernel, dim3(8), dim3(256), 0, stream, F, osg, osb, FTg, cvec);

  // ---- quadratic attention scores -> scC ----
  hipLaunchKernelGGL(score_mfma, dim3(4, 2, G), dim3(256), 0, stream, Eqk, osg, osb, scC);

  // ---- fused quad + lin + gate -> T2 ----
  hipLaunchKernelGGL(quadlin_mfma, dim3(16, 2, G), dim3(256), 0, stream,
                     scC, h, Eqk, FTg, cvec, T2);

  // ---- out branch ----
  hipLaunchKernelGGL(ln1024_kernel, dim3(N), dim3(256), 0, stream, T2);
  hipLaunchKernelGGL(gemm_mfma_silu, dim3(4, N/128), dim3(256), 0, stream,
                     T2, 1024, WoutT, 1024, 0, scC, 512, Bout, 1024);
  hipLaunchKernelGGL(dwconv_final, dim3(8, N/32), dim3(256), 0, stream,
                     scC, out_conv, x, (float*)d_out, N);
}